// Round 2
// baseline (2585.975 us; speedup 1.0000x reference)
//
#include <hip/hip_runtime.h>
#include <math.h>

#define N_TOK 3136
#define CD    256
#define NHD   8
#define DH    32
#define DFFD  1024
#define SCALE 0.17677669529663687f  /* 32^-0.5 */

// ---------------------------------------------------------------- utils
__device__ __forceinline__ unsigned long long sx64(unsigned long long v, int m) {
  unsigned lo = (unsigned)__shfl_xor((int)(unsigned)(v & 0xffffffffull), m, 64);
  unsigned hi = (unsigned)__shfl_xor((int)(unsigned)(v >> 32), m, 64);
  return ((unsigned long long)hi << 32) | lo;
}

__device__ __forceinline__ unsigned f2mono(float v) {
  unsigned b = __float_as_uint(v);
  return (b & 0x80000000u) ? ~b : (b | 0x80000000u);
}

// ------------------------------------------------- transpose (32x32 tiles)
// out[c][r] = in[r][c]; R, C multiples of 32. grid (C/32, R/32), block 256.
__global__ __launch_bounds__(256) void transpose_k(const float* __restrict__ in,
    float* __restrict__ out, int R, int C) {
  __shared__ float ls[32][33];
  const int c0 = blockIdx.x * 32, r0 = blockIdx.y * 32;
  const int tx = threadIdx.x & 31, ty = threadIdx.x >> 5;  // ty 0..7
#pragma unroll
  for (int j = 0; j < 4; ++j) {
    int r = ty + j * 8;
    ls[r][tx] = in[(size_t)(r0 + r) * C + c0 + tx];
  }
  __syncthreads();
#pragma unroll
  for (int j = 0; j < 4; ++j) {
    int cc = ty + j * 8;
    out[(size_t)(c0 + cc) * R + r0 + tx] = ls[tx][cc];
  }
}

// ------------------------------------------------------------- im2col 3x3
// col[pix][ci*9 + ky*3 + kx] = src[ci][y+ky-1][x+kx-1] (zero-padded SAME)
__global__ __launch_bounds__(256) void im2col_k(const float* __restrict__ src,
    float* __restrict__ col) {
  int e = blockIdx.x * 256 + threadIdx.x;     // < 3136*2304 exactly
  int pix = e / 2304;
  int kk = e - pix * 2304;
  int ci = kk / 9;
  int r = kk - ci * 9;
  int ky = r / 3, kx = r - ky * 3;
  int y = pix / 56, x = pix - y * 56;
  int yy = y + ky - 1, xx = x + kx - 1;
  float v = (yy >= 0 && yy < 56 && xx >= 0 && xx < 56)
                ? src[(size_t)ci * 3136 + yy * 56 + xx] : 0.f;
  col[(size_t)e] = v;
}

// --------------------------------------------------------------- GEMM NT
// C[m][n] = sum_k A[m][k]*B[n][k] (+bias[n]) (+relu). M,N %64==0, K %16==0.
// grid (N/64, M/64), block 256.
template <int RELU>
__global__ __launch_bounds__(256) void gemm_nt(const float* __restrict__ A,
    const float* __restrict__ B, const float* __restrict__ bias,
    float* __restrict__ C, int M, int N, int K) {
  __shared__ float As[16][68];
  __shared__ float Bs[16][68];
  const int n0 = blockIdx.x * 64;
  const int m0 = blockIdx.y * 64;
  const int t = threadIdx.x;
  const int tx = t & 15, ty = t >> 4;
  const int lr = t >> 2;           // 0..63
  const int lk = (t & 3) << 2;     // 0,4,8,12
  const float* Ap = A + (size_t)(m0 + lr) * K + lk;
  const float* Bp = B + (size_t)(n0 + lr) * K + lk;
  float acc[4][4] = {};
  for (int k0 = 0; k0 < K; k0 += 16) {
    const float4 a = *(const float4*)(Ap + k0);
    const float4 b = *(const float4*)(Bp + k0);
    __syncthreads();
    As[lk + 0][lr] = a.x; As[lk + 1][lr] = a.y; As[lk + 2][lr] = a.z; As[lk + 3][lr] = a.w;
    Bs[lk + 0][lr] = b.x; Bs[lk + 1][lr] = b.y; Bs[lk + 2][lr] = b.z; Bs[lk + 3][lr] = b.w;
    __syncthreads();
#pragma unroll
    for (int k = 0; k < 16; ++k) {
      const float4 av = *(const float4*)&As[k][ty << 2];
      const float4 bv = *(const float4*)&Bs[k][tx << 2];
      acc[0][0] += av.x * bv.x; acc[0][1] += av.x * bv.y; acc[0][2] += av.x * bv.z; acc[0][3] += av.x * bv.w;
      acc[1][0] += av.y * bv.x; acc[1][1] += av.y * bv.y; acc[1][2] += av.y * bv.z; acc[1][3] += av.y * bv.w;
      acc[2][0] += av.z * bv.x; acc[2][1] += av.z * bv.y; acc[2][2] += av.z * bv.z; acc[2][3] += av.z * bv.w;
      acc[3][0] += av.w * bv.x; acc[3][1] += av.w * bv.y; acc[3][2] += av.w * bv.z; acc[3][3] += av.w * bv.w;
    }
  }
  float4 bb = make_float4(0.f, 0.f, 0.f, 0.f);
  if (bias) bb = *(const float4*)&bias[n0 + (tx << 2)];
#pragma unroll
  for (int i2 = 0; i2 < 4; ++i2) {
    int m = m0 + (ty << 2) + i2;
    float4 r;
    r.x = acc[i2][0] + bb.x; r.y = acc[i2][1] + bb.y;
    r.z = acc[i2][2] + bb.z; r.w = acc[i2][3] + bb.w;
    if (RELU) {
      r.x = fmaxf(r.x, 0.f); r.y = fmaxf(r.y, 0.f);
      r.z = fmaxf(r.z, 0.f); r.w = fmaxf(r.w, 0.f);
    }
    *(float4*)&C[(size_t)m * N + n0 + (tx << 2)] = r;
  }
}

// ------------------------------------------------------------ conv2 (8ch)
// t1: [3136][128] (pix-major from conv1 gemm). gp[pix*8+co] = sigmoid(conv)
__global__ __launch_bounds__(256) void conv2_k(const float* __restrict__ t1,
    const float* __restrict__ w, const float* __restrict__ b,
    float* __restrict__ gp) {
  __shared__ float ws3[9 * 8 * 132];
  const int t = threadIdx.x;
  for (int e = t; e < 9216; e += 256) {
    int r = e >> 10;            // e/1024
    int rem = e & 1023;
    int co = rem >> 7;
    int ci = rem & 127;
    ws3[(r * 8 + co) * 132 + ci] = w[((size_t)co * 128 + ci) * 9 + r];
  }
  __syncthreads();
  const int pix = blockIdx.x * 32 + (t >> 3);
  const int co = t & 7;
  const int y = pix / 56, x = pix - y * 56;
  float acc = b[co];
  for (int ky = 0; ky < 3; ++ky) {
    int yy = y + ky - 1;
    if (yy < 0 || yy >= 56) continue;
    for (int kx = 0; kx < 3; ++kx) {
      int xx = x + kx - 1;
      if (xx < 0 || xx >= 56) continue;
      const float4* tp = (const float4*)&t1[(size_t)(yy * 56 + xx) * 128];
      const float* wp = &ws3[((ky * 3 + kx) * 8 + co) * 132];
#pragma unroll
      for (int c4 = 0; c4 < 32; ++c4) {
        const float4 tv = tp[c4];
        const float4 wv = *(const float4*)&wp[c4 * 4];
        acc += tv.x * wv.x + tv.y * wv.y + tv.z * wv.z + tv.w * wv.w;
      }
    }
  }
  gp[pix * 8 + co] = 1.f / (1.f + expf(-acc));
}

// ------------------------------------------------------------- row ||x||^2
__global__ __launch_bounds__(64) void rowsq_k(const float* __restrict__ x,
                                              float* __restrict__ sq) {
  const int i = blockIdx.x, lane = threadIdx.x;
  const float4 v = ((const float4*)&x[(size_t)i * CD])[lane];
  float s = v.x * v.x + v.y * v.y + v.z * v.z + v.w * v.w;
#pragma unroll
  for (int m = 1; m < 64; m <<= 1) s += __shfl_xor(s, m, 64);
  if (lane == 0) sq[i] = s;
}

// -------------------------------------------------- top-16 NN + in-degree
// One block per row i. d2[j] = (sq[i]-2G[i][j])+sq[j]. 16 iterative
// lexicographic-min extractions (ties -> smaller j), atomicAdd near[j].
__global__ __launch_bounds__(256) void topk_k(const float* __restrict__ G,
    const float* __restrict__ sq, int* __restrict__ near) {
  __shared__ unsigned long long wmin[4];
  const int i = blockIdx.x;
  const int t = threadIdx.x;
  const float sqi = sq[i];
  unsigned long long key[13];
#pragma unroll
  for (int e = 0; e < 13; ++e) {
    int j = t + (e << 8);
    float d2 = INFINITY;
    if (j < N_TOK) d2 = (sqi - 2.f * G[(size_t)i * N_TOK + j]) + sq[j];
    key[e] = ((unsigned long long)f2mono(d2) << 32) | (unsigned)j;
  }
  unsigned long long last = 0ull;
#pragma unroll 1
  for (int r = 0; r < 16; ++r) {
    unsigned long long best = ~0ull;
#pragma unroll
    for (int e = 0; e < 13; ++e) {
      bool ok = (key[e] > last) && (key[e] < best);
      best = ok ? key[e] : best;
    }
#pragma unroll
    for (int m = 1; m < 64; m <<= 1) {
      unsigned long long o = sx64(best, m);
      best = (o < best) ? o : best;
    }
    __syncthreads();                 // protect wmin from previous round reads
    if ((t & 63) == 0) wmin[t >> 6] = best;
    __syncthreads();
    unsigned long long b0 = wmin[0] < wmin[1] ? wmin[0] : wmin[1];
    unsigned long long b1 = wmin[2] < wmin[3] ? wmin[2] : wmin[3];
    best = b0 < b1 ? b0 : b1;
    if (t == 0) atomicAdd(&near[(unsigned)(best & 0xffffffffu)], 1);
    last = best;
  }
}

// ------------------------------------------------------------- max(near)
__global__ __launch_bounds__(256) void nearmax_k(const int* __restrict__ near,
                                                 int* __restrict__ nmax) {
  __shared__ int sm[4];
  const int t = threadIdx.x;
  int m = 0;
  for (int j = t; j < N_TOK; j += 256) m = max(m, near[j]);
#pragma unroll
  for (int s = 1; s < 64; s <<= 1) m = max(m, __shfl_xor(m, s, 64));
  if ((t & 63) == 0) sm[t >> 6] = m;
  __syncthreads();
  if (t == 0) nmax[0] = max(max(sm[0], sm[1]), max(sm[2], sm[3]));
}

// ------------------------------------------------ qk_in = x + emb[ni(near)]
__global__ __launch_bounds__(256) void qkin_k(const float* __restrict__ x,
    const int* __restrict__ near, const int* __restrict__ nmax,
    const float* __restrict__ emb, float* __restrict__ qkin) {
  const int i = blockIdx.x, t = threadIdx.x;
  const float nf = (float)near[i], mf = (float)nmax[0];
  const int ni = (int)(nf / mf * 9.0f);
  qkin[(size_t)i * CD + t] = x[(size_t)i * CD + t] + emb[ni * CD + t];
}

// -------------------------------------------------------- flash attention
// grid (49, 8): 64-query tile per block, head = blockIdx.y. 256 threads:
// thread -> (ii = t>>3 in 0..31 -> rows ii, ii+32 ; qq = t&7 -> 4 cols).
__global__ __launch_bounds__(256) void attn_k(const float* __restrict__ Qm,
    const float* __restrict__ Km, const float* __restrict__ Vm,
    const float* __restrict__ gp, float* __restrict__ Om) {
  const int h = blockIdx.y;
  const int i0 = blockIdx.x * 64;
  const int t = threadIdx.x;
  const int ii = t >> 3;
  const int qq = t & 7;
  const int c0 = qq << 2;
  __shared__ float Kt[32][36];   // [d][j]
  __shared__ float Vs[32][40];   // [j][d]
  __shared__ float Ps[64][36];   // [i][j]
  __shared__ float gpj[32];

  float4 qa[8], qb[8];
  {
    const float* qpa = &Qm[(size_t)(i0 + ii) * CD + h * DH];
    const float* qpb = &Qm[(size_t)(i0 + ii + 32) * CD + h * DH];
#pragma unroll
    for (int u = 0; u < 8; ++u) {
      float4 v = *(const float4*)(qpa + 4 * u);
      qa[u] = make_float4(v.x * SCALE, v.y * SCALE, v.z * SCALE, v.w * SCALE);
      v = *(const float4*)(qpb + 4 * u);
      qb[u] = make_float4(v.x * SCALE, v.y * SCALE, v.z * SCALE, v.w * SCALE);
    }
  }
  const float gpa = gp[(size_t)(i0 + ii) * NHD + h];
  const float gpb = gp[(size_t)(i0 + ii + 32) * NHD + h];
  float ma = -INFINITY, mb = -INFINITY, la = 0.f, lb = 0.f;
  float4 oa = make_float4(0.f, 0.f, 0.f, 0.f);
  float4 ob = make_float4(0.f, 0.f, 0.f, 0.f);

  for (int j0 = 0; j0 < N_TOK; j0 += 32) {
    __syncthreads();
    {
      const float4 kv = *(const float4*)&Km[(size_t)(j0 + ii) * CD + h * DH + c0];
      Kt[c0 + 0][ii] = kv.x; Kt[c0 + 1][ii] = kv.y;
      Kt[c0 + 2][ii] = kv.z; Kt[c0 + 3][ii] = kv.w;
      const float4 vv = *(const float4*)&Vm[(size_t)(j0 + ii) * CD + h * DH + c0];
      *(float4*)&Vs[ii][c0] = vv;
      if (t < 32) gpj[t] = gp[(size_t)(j0 + t) * NHD + h];
    }
    __syncthreads();
    float4 sa = make_float4(0.f, 0.f, 0.f, 0.f);
    float4 sb = make_float4(0.f, 0.f, 0.f, 0.f);
#pragma unroll
    for (int dc = 0; dc < 8; ++dc) {
      const float4 k0 = *(const float4*)&Kt[4 * dc + 0][c0];
      const float4 k1 = *(const float4*)&Kt[4 * dc + 1][c0];
      const float4 k2 = *(const float4*)&Kt[4 * dc + 2][c0];
      const float4 k3 = *(const float4*)&Kt[4 * dc + 3][c0];
      sa.x += qa[dc].x * k0.x + qa[dc].y * k1.x + qa[dc].z * k2.x + qa[dc].w * k3.x;
      sa.y += qa[dc].x * k0.y + qa[dc].y * k1.y + qa[dc].z * k2.y + qa[dc].w * k3.y;
      sa.z += qa[dc].x * k0.z + qa[dc].y * k1.z + qa[dc].z * k2.z + qa[dc].w * k3.z;
      sa.w += qa[dc].x * k0.w + qa[dc].y * k1.w + qa[dc].z * k2.w + qa[dc].w * k3.w;
      sb.x += qb[dc].x * k0.x + qb[dc].y * k1.x + qb[dc].z * k2.x + qb[dc].w * k3.x;
      sb.y += qb[dc].x * k0.y + qb[dc].y * k1.y + qb[dc].z * k2.y + qb[dc].w * k3.y;
      sb.z += qb[dc].x * k0.z + qb[dc].y * k1.z + qb[dc].z * k2.z + qb[dc].w * k3.z;
      sb.w += qb[dc].x * k0.w + qb[dc].y * k1.w + qb[dc].z * k2.w + qb[dc].w * k3.w;
    }
    const float g0 = gpj[c0 + 0], g1 = gpj[c0 + 1], g2 = gpj[c0 + 2], g3 = gpj[c0 + 3];
    sa.x += fabsf(gpa - g0); sa.y += fabsf(gpa - g1);
    sa.z += fabsf(gpa - g2); sa.w += fabsf(gpa - g3);
    sb.x += fabsf(gpb - g0); sb.y += fabsf(gpb - g1);
    sb.z += fabsf(gpb - g2); sb.w += fabsf(gpb - g3);
    // --- online softmax row a
    float mxa = fmaxf(fmaxf(sa.x, sa.y), fmaxf(sa.z, sa.w));
    mxa = fmaxf(mxa, __shfl_xor(mxa, 1, 64));
    mxa = fmaxf(mxa, __shfl_xor(mxa, 2, 64));
    mxa = fmaxf(mxa, __shfl_xor(mxa, 4, 64));
    const float mna = fmaxf(ma, mxa);
    const float ca = __expf(ma - mna);
    float4 pa;
    pa.x = __expf(sa.x - mna); pa.y = __expf(sa.y - mna);
    pa.z = __expf(sa.z - mna); pa.w = __expf(sa.w - mna);
    float psa = pa.x + pa.y + pa.z + pa.w;
    psa += __shfl_xor(psa, 1, 64); psa += __shfl_xor(psa, 2, 64); psa += __shfl_xor(psa, 4, 64);
    la = la * ca + psa; ma = mna;
    oa.x *= ca; oa.y *= ca; oa.z *= ca; oa.w *= ca;
    *(float4*)&Ps[ii][c0] = pa;
    // --- online softmax row b
    float mxb = fmaxf(fmaxf(sb.x, sb.y), fmaxf(sb.z, sb.w));
    mxb = fmaxf(mxb, __shfl_xor(mxb, 1, 64));
    mxb = fmaxf(mxb, __shfl_xor(mxb, 2, 64));
    mxb = fmaxf(mxb, __shfl_xor(mxb, 4, 64));
    const float mnb = fmaxf(mb, mxb);
    const float cb = __expf(mb - mnb);
    float4 pb;
    pb.x = __expf(sb.x - mnb); pb.y = __expf(sb.y - mnb);
    pb.z = __expf(sb.z - mnb); pb.w = __expf(sb.w - mnb);
    float psb = pb.x + pb.y + pb.z + pb.w;
    psb += __shfl_xor(psb, 1, 64); psb += __shfl_xor(psb, 2, 64); psb += __shfl_xor(psb, 4, 64);
    lb = lb * cb + psb; mb = mnb;
    ob.x *= cb; ob.y *= cb; ob.z *= cb; ob.w *= cb;
    *(float4*)&Ps[ii + 32][c0] = pb;
    __syncthreads();
    // --- PV
#pragma unroll
    for (int jc = 0; jc < 8; ++jc) {
      const float4 pva = *(const float4*)&Ps[ii][4 * jc];
      const float4 pvb = *(const float4*)&Ps[ii + 32][4 * jc];
      const float4 v0 = *(const float4*)&Vs[4 * jc + 0][c0];
      const float4 v1 = *(const float4*)&Vs[4 * jc + 1][c0];
      const float4 v2 = *(const float4*)&Vs[4 * jc + 2][c0];
      const float4 v3 = *(const float4*)&Vs[4 * jc + 3][c0];
      oa.x += pva.x * v0.x + pva.y * v1.x + pva.z * v2.x + pva.w * v3.x;
      oa.y += pva.x * v0.y + pva.y * v1.y + pva.z * v2.y + pva.w * v3.y;
      oa.z += pva.x * v0.z + pva.y * v1.z + pva.z * v2.z + pva.w * v3.z;
      oa.w += pva.x * v0.w + pva.y * v1.w + pva.z * v2.w + pva.w * v3.w;
      ob.x += pvb.x * v0.x + pvb.y * v1.x + pvb.z * v2.x + pvb.w * v3.x;
      ob.y += pvb.x * v0.y + pvb.y * v1.y + pvb.z * v2.y + pvb.w * v3.y;
      ob.z += pvb.x * v0.z + pvb.y * v1.z + pvb.z * v2.z + pvb.w * v3.z;
      ob.w += pvb.x * v0.w + pvb.y * v1.w + pvb.z * v2.w + pvb.w * v3.w;
    }
  }
  const float ra = 1.f / la, rb = 1.f / lb;
  float4 w0 = make_float4(oa.x * ra, oa.y * ra, oa.z * ra, oa.w * ra);
  *(float4*)&Om[(size_t)(i0 + ii) * CD + h * DH + c0] = w0;
  float4 w1 = make_float4(ob.x * rb, ob.y * rb, ob.z * rb, ob.w * rb);
  *(float4*)&Om[(size_t)(i0 + ii + 32) * CD + h * DH + c0] = w1;
}

// -------------------------------------------------- LayerNorm (+residual)
__global__ __launch_bounds__(256) void ln_k(const float* __restrict__ xin,
    const float* __restrict__ add, const float* __restrict__ g,
    const float* __restrict__ b, float* __restrict__ xout) {
  __shared__ float red1[4];
  __shared__ float red2[4];
  const int i = blockIdx.x, t = threadIdx.x;
  float v = xin[(size_t)i * CD + t];
  if (add) v += add[(size_t)i * CD + t];
  float s = v;
#pragma unroll
  for (int m = 1; m < 64; m <<= 1) s += __shfl_xor(s, m, 64);
  if ((t & 63) == 0) red1[t >> 6] = s;
  __syncthreads();
  const float mean = (red1[0] + red1[1] + red1[2] + red1[3]) * (1.f / 256.f);
  const float d = v - mean;
  float s2 = d * d;
#pragma unroll
  for (int m = 1; m < 64; m <<= 1) s2 += __shfl_xor(s2, m, 64);
  if ((t & 63) == 0) red2[t >> 6] = s2;
  __syncthreads();
  const float var = (red2[0] + red2[1] + red2[2] + red2[3]) * (1.f / 256.f);
  xout[(size_t)i * CD + t] = d * rsqrtf(var + 1e-5f) * g[t] + b[t];
}

// ---------------------------------------------------------------- launch
extern "C" void kernel_launch(void* const* d_in, const int* in_sizes, int n_in,
                              void* d_out, int out_size, void* d_ws, size_t ws_size,
                              hipStream_t stream) {
  const float* src  = (const float*)d_in[0];
  const float* c1w  = (const float*)d_in[1];
  const float* c1b  = (const float*)d_in[2];
  const float* c2w  = (const float*)d_in[3];
  const float* c2b  = (const float*)d_in[4];
  const float* nemb = (const float*)d_in[5];
  const float* Wq   = (const float*)d_in[6];
  const float* bq   = (const float*)d_in[7];
  const float* Wk   = (const float*)d_in[8];
  const float* bk   = (const float*)d_in[9];
  const float* Wv   = (const float*)d_in[10];
  const float* bv   = (const float*)d_in[11];
  const float* Wo   = (const float*)d_in[12];
  const float* bo   = (const float*)d_in[13];
  const float* W1   = (const float*)d_in[14];
  const float* b1   = (const float*)d_in[15];
  const float* W2   = (const float*)d_in[16];
  const float* b2   = (const float*)d_in[17];
  const float* ln1g = (const float*)d_in[18];
  const float* ln1b = (const float*)d_in[19];
  const float* ln2g = (const float*)d_in[20];
  const float* ln2b = (const float*)d_in[21];
  const float* ng   = (const float*)d_in[22];
  const float* nb   = (const float*)d_in[23];

  float* ws = (float*)d_ws;
  const size_t NC = (size_t)N_TOK * CD;          // 802816
  float* X    = ws;
  float* QKIN = X + NC;
  float* QB   = QKIN + NC;
  float* KB   = QB + NC;
  float* VB   = KB + NC;
  float* O1   = VB + NC;
  float* TMP  = O1 + NC;
  float* FF1  = TMP + NC;                        // 3136*1024
  float* G    = FF1 + (size_t)N_TOK * DFFD;      // 3136*3136 (also im2col)
  float* T1   = G + (size_t)N_TOK * N_TOK;       // 3136*128
  float* GP   = T1 + (size_t)N_TOK * 128;        // 3136*8
  float* SQF  = GP + (size_t)N_TOK * NHD;        // 3136
  int*   NEAR = (int*)(SQF + N_TOK);             // 3136 ints
  int*   NMAX = NEAR + N_TOK;                    // 1 int

  // conv positional encoder: im2col + gemm(relu) + conv2(sigmoid)
  im2col_k<<<28224, 256, 0, stream>>>(src, G);
  gemm_nt<1><<<dim3(2, 49), 256, 0, stream>>>(G, c1w, c1b, T1, N_TOK, 128, 2304);
  conv2_k<<<98, 256, 0, stream>>>(T1, c2w, c2b, GP);
  // tokens: x[tok][ch] = src[ch][tok]
  transpose_k<<<dim3(98, 8), 256, 0, stream>>>(src, X, 256, N_TOK);

  for (int l = 0; l < 4; ++l) {
    // ---- kNN graph -> near counts
    rowsq_k<<<N_TOK, 64, 0, stream>>>(X, SQF);
    gemm_nt<0><<<dim3(49, 49), 256, 0, stream>>>(X, X, nullptr, G, N_TOK, N_TOK, CD);
    hipMemsetAsync(NEAR, 0, N_TOK * sizeof(int), stream);
    topk_k<<<N_TOK, 256, 0, stream>>>(G, SQF, NEAR);
    nearmax_k<<<1, 256, 0, stream>>>(NEAR, NMAX);
    qkin_k<<<N_TOK, 256, 0, stream>>>(X, NEAR, NMAX, nemb, QKIN);
    // ---- attention
    gemm_nt<0><<<dim3(4, 49), 256, 0, stream>>>(QKIN, Wq + (size_t)l * 65536, bq + l * 256, QB, N_TOK, CD, CD);
    gemm_nt<0><<<dim3(4, 49), 256, 0, stream>>>(QKIN, Wk + (size_t)l * 65536, bk + l * 256, KB, N_TOK, CD, CD);
    gemm_nt<0><<<dim3(4, 49), 256, 0, stream>>>(X,    Wv + (size_t)l * 65536, bv + l * 256, VB, N_TOK, CD, CD);
    attn_k<<<dim3(49, 8), 256, 0, stream>>>(QB, KB, VB, GP, O1);
    gemm_nt<0><<<dim3(4, 49), 256, 0, stream>>>(O1, Wo + (size_t)l * 65536, bo + l * 256, TMP, N_TOK, CD, CD);
    ln_k<<<N_TOK, 256, 0, stream>>>(X, TMP, ln1g + l * 256, ln1b + l * 256, X);
    // ---- FFN
    gemm_nt<1><<<dim3(16, 49), 256, 0, stream>>>(X, W1 + (size_t)l * 262144, b1 + l * 1024, FF1, N_TOK, DFFD, CD);
    gemm_nt<0><<<dim3(4, 49), 256, 0, stream>>>(FF1, W2 + (size_t)l * 262144, b2 + l * 256, TMP, N_TOK, CD, DFFD);
    ln_k<<<N_TOK, 256, 0, stream>>>(X, TMP, ln2g + l * 256, ln2b + l * 256, X);
  }
  // final LN + transpose to [1,C,H,W]
  ln_k<<<N_TOK, 256, 0, stream>>>(X, nullptr, ng, nb, TMP);
  transpose_k<<<dim3(8, 98), 256, 0, stream>>>(TMP, (float*)d_out, N_TOK, 256);
}

// Round 3
// 1286.076 us; speedup vs baseline: 2.0107x; 2.0107x over previous
//
#include <hip/hip_runtime.h>
#include <math.h>

#define N_TOK 3136
#define CD    256
#define NHD   8
#define DH    32
#define DFFD  1024
#define SCALE 0.17677669529663687f  /* 32^-0.5 */

typedef __attribute__((ext_vector_type(8))) short short8v;
typedef __attribute__((ext_vector_type(4))) float f32x4;

// ---------------------------------------------------------------- utils
__device__ __forceinline__ unsigned long long sx64(unsigned long long v, int m) {
  unsigned lo = (unsigned)__shfl_xor((int)(unsigned)(v & 0xffffffffull), m, 64);
  unsigned hi = (unsigned)__shfl_xor((int)(unsigned)(v >> 32), m, 64);
  return ((unsigned long long)hi << 32) | lo;
}

__device__ __forceinline__ unsigned f2mono(float v) {
  unsigned b = __float_as_uint(v);
  return (b & 0x80000000u) ? ~b : (b | 0x80000000u);
}

// fp32 -> bf16 round-to-nearest-even
__device__ __forceinline__ short bfr(float f) {
  unsigned u = __float_as_uint(f);
  unsigned r = (u + 0x7fffu + ((u >> 16) & 1u)) >> 16;
  return (short)r;
}

__device__ __forceinline__ short8v cvt8(float4 a, float4 b) {
  short8v r;
  r[0] = bfr(a.x); r[1] = bfr(a.y); r[2] = bfr(a.z); r[3] = bfr(a.w);
  r[4] = bfr(b.x); r[5] = bfr(b.y); r[6] = bfr(b.z); r[7] = bfr(b.w);
  return r;
}

// ------------------------------------------------- transpose (32x32 tiles)
__global__ __launch_bounds__(256) void transpose_k(const float* __restrict__ in,
    float* __restrict__ out, int R, int C) {
  __shared__ float ls[32][33];
  const int c0 = blockIdx.x * 32, r0 = blockIdx.y * 32;
  const int tx = threadIdx.x & 31, ty = threadIdx.x >> 5;
#pragma unroll
  for (int j = 0; j < 4; ++j) {
    int r = ty + j * 8;
    ls[r][tx] = in[(size_t)(r0 + r) * C + c0 + tx];
  }
  __syncthreads();
#pragma unroll
  for (int j = 0; j < 4; ++j) {
    int cc = ty + j * 8;
    out[(size_t)(c0 + cc) * R + r0 + tx] = ls[tx][cc];
  }
}

// ------------------------------------------------------------- im2col 3x3
__global__ __launch_bounds__(256) void im2col_k(const float* __restrict__ src,
    float* __restrict__ col) {
  int e = blockIdx.x * 256 + threadIdx.x;
  int pix = e / 2304;
  int kk = e - pix * 2304;
  int ci = kk / 9;
  int r = kk - ci * 9;
  int ky = r / 3, kx = r - ky * 3;
  int y = pix / 56, x = pix - y * 56;
  int yy = y + ky - 1, xx = x + kx - 1;
  float v = (yy >= 0 && yy < 56 && xx >= 0 && xx < 56)
                ? src[(size_t)ci * 3136 + yy * 56 + xx] : 0.f;
  col[(size_t)e] = v;
}

// ------------------------------------------ bf16 MFMA GEMM NT (fp32 I/O)
// C[m][n] = sum_k A[m][k]*B[n][k] (+bias)(+relu). M%64==0, N%64==0, K%32==0.
// grid (N/64, M/64), 256 thr = 4 waves; wave (wr,wc) owns 32x32 quadrant.
template <int RELU>
__global__ __launch_bounds__(256) void gemm_bt_bf16(const float* __restrict__ A,
    const float* __restrict__ B, const float* __restrict__ bias,
    float* __restrict__ C, int M, int N, int K) {
  __shared__ __align__(16) short As[64][40];   // 80B row stride
  __shared__ __align__(16) short Bs[64][40];
  const int n0 = blockIdx.x * 64;
  const int m0 = blockIdx.y * 64;
  const int t = threadIdx.x;
  const int w = t >> 6, l = t & 63;
  const int g = l >> 4, c = l & 15;
  const int wr = w >> 1, wc = w & 1;
  const int sr = t >> 2, seg = t & 3;          // staging row/segment
  const float* Ap = A + (size_t)(m0 + sr) * K + seg * 8;
  const float* Bp = B + (size_t)(n0 + sr) * K + seg * 8;
  f32x4 acc[2][2] = {};
  for (int k0 = 0; k0 < K; k0 += 32) {
    const float4 a1 = *(const float4*)(Ap + k0);
    const float4 a2 = *(const float4*)(Ap + k0 + 4);
    const float4 b1 = *(const float4*)(Bp + k0);
    const float4 b2 = *(const float4*)(Bp + k0 + 4);
    __syncthreads();
    *(short8v*)&As[sr][seg * 8] = cvt8(a1, a2);
    *(short8v*)&Bs[sr][seg * 8] = cvt8(b1, b2);
    __syncthreads();
    short8v af[2], bf[2];
#pragma unroll
    for (int mi = 0; mi < 2; ++mi)
      af[mi] = *(const short8v*)&As[wr * 32 + mi * 16 + c][g * 8];
#pragma unroll
    for (int ni = 0; ni < 2; ++ni)
      bf[ni] = *(const short8v*)&Bs[wc * 32 + ni * 16 + c][g * 8];
#pragma unroll
    for (int mi = 0; mi < 2; ++mi)
#pragma unroll
      for (int ni = 0; ni < 2; ++ni)
        acc[mi][ni] = __builtin_amdgcn_mfma_f32_16x16x32_bf16(
            af[mi], bf[ni], acc[mi][ni], 0, 0, 0);
  }
#pragma unroll
  for (int mi = 0; mi < 2; ++mi) {
#pragma unroll
    for (int ni = 0; ni < 2; ++ni) {
      const int col = n0 + wc * 32 + ni * 16 + c;
      const float bb = bias ? bias[col] : 0.f;
#pragma unroll
      for (int q = 0; q < 4; ++q) {
        const int m = m0 + wr * 32 + mi * 16 + g * 4 + q;
        float v = acc[mi][ni][q] + bb;
        if (RELU) v = fmaxf(v, 0.f);
        C[(size_t)m * N + col] = v;
      }
    }
  }
}

// -------------------------------------- fp32 symmetric Gram: G = X X^T
// Upper-triangle block grid (1225 blocks), stores tile and its mirror.
__global__ __launch_bounds__(256) void gemm_syr_k(const float* __restrict__ A,
    float* __restrict__ C, int Nn, int K) {
  __shared__ float As[16][68];
  __shared__ float Bs[16][68];
  int bid = blockIdx.x;
  int bi = (int)((sqrtf(8.f * (float)bid + 1.f) - 1.f) * 0.5f);
  while ((bi + 1) * (bi + 2) / 2 <= bid) ++bi;
  while (bi * (bi + 1) / 2 > bid) --bi;
  const int bj = bid - bi * (bi + 1) / 2;
  const int m0 = bi * 64, n0 = bj * 64;
  const int t = threadIdx.x;
  const int tx = t & 15, ty = t >> 4;
  const int lr = t >> 2;
  const int lk = (t & 3) << 2;
  const float* Ap = A + (size_t)(m0 + lr) * K + lk;
  const float* Bp = A + (size_t)(n0 + lr) * K + lk;
  float acc[4][4] = {};
  for (int k0 = 0; k0 < K; k0 += 16) {
    const float4 a = *(const float4*)(Ap + k0);
    const float4 b = *(const float4*)(Bp + k0);
    __syncthreads();
    As[lk + 0][lr] = a.x; As[lk + 1][lr] = a.y; As[lk + 2][lr] = a.z; As[lk + 3][lr] = a.w;
    Bs[lk + 0][lr] = b.x; Bs[lk + 1][lr] = b.y; Bs[lk + 2][lr] = b.z; Bs[lk + 3][lr] = b.w;
    __syncthreads();
#pragma unroll
    for (int k = 0; k < 16; ++k) {
      const float4 av = *(const float4*)&As[k][ty << 2];
      const float4 bv = *(const float4*)&Bs[k][tx << 2];
      acc[0][0] += av.x * bv.x; acc[0][1] += av.x * bv.y; acc[0][2] += av.x * bv.z; acc[0][3] += av.x * bv.w;
      acc[1][0] += av.y * bv.x; acc[1][1] += av.y * bv.y; acc[1][2] += av.y * bv.z; acc[1][3] += av.y * bv.w;
      acc[2][0] += av.z * bv.x; acc[2][1] += av.z * bv.y; acc[2][2] += av.z * bv.z; acc[2][3] += av.z * bv.w;
      acc[3][0] += av.w * bv.x; acc[3][1] += av.w * bv.y; acc[3][2] += av.w * bv.z; acc[3][3] += av.w * bv.w;
    }
  }
#pragma unroll
  for (int i2 = 0; i2 < 4; ++i2) {
    const int m = m0 + (ty << 2) + i2;
#pragma unroll
    for (int jj = 0; jj < 4; ++jj) {
      const int n = n0 + (tx << 2) + jj;
      const float v = acc[i2][jj];
      C[(size_t)m * Nn + n] = v;
      C[(size_t)n * Nn + m] = v;
    }
  }
}

// ------------------------------------------------------------ conv2 (8ch)
__global__ __launch_bounds__(256) void conv2_k(const float* __restrict__ t1,
    const float* __restrict__ w, const float* __restrict__ b,
    float* __restrict__ gp) {
  __shared__ float ws3[9 * 8 * 132];
  const int t = threadIdx.x;
  for (int e = t; e < 9216; e += 256) {
    int r = e >> 10;
    int rem = e & 1023;
    int co = rem >> 7;
    int ci = rem & 127;
    ws3[(r * 8 + co) * 132 + ci] = w[((size_t)co * 128 + ci) * 9 + r];
  }
  __syncthreads();
  const int pix = blockIdx.x * 32 + (t >> 3);
  const int co = t & 7;
  const int y = pix / 56, x = pix - y * 56;
  float acc = b[co];
  for (int ky = 0; ky < 3; ++ky) {
    int yy = y + ky - 1;
    if (yy < 0 || yy >= 56) continue;
    for (int kx = 0; kx < 3; ++kx) {
      int xx = x + kx - 1;
      if (xx < 0 || xx >= 56) continue;
      const float4* tp = (const float4*)&t1[(size_t)(yy * 56 + xx) * 128];
      const float* wp = &ws3[((ky * 3 + kx) * 8 + co) * 132];
#pragma unroll
      for (int c4 = 0; c4 < 32; ++c4) {
        const float4 tv = tp[c4];
        const float4 wv = *(const float4*)&wp[c4 * 4];
        acc += tv.x * wv.x + tv.y * wv.y + tv.z * wv.z + tv.w * wv.w;
      }
    }
  }
  gp[pix * 8 + co] = 1.f / (1.f + expf(-acc));
}

// ------------------------------------------------------------- row ||x||^2
__global__ __launch_bounds__(64) void rowsq_k(const float* __restrict__ x,
                                              float* __restrict__ sq) {
  const int i = blockIdx.x, lane = threadIdx.x;
  const float4 v = ((const float4*)&x[(size_t)i * CD])[lane];
  float s = v.x * v.x + v.y * v.y + v.z * v.z + v.w * v.w;
#pragma unroll
  for (int m = 1; m < 64; m <<= 1) s += __shfl_xor(s, m, 64);
  if (lane == 0) sq[i] = s;
}

// -------------------------------------------------- top-16 NN + in-degree
__global__ __launch_bounds__(256) void topk_k(const float* __restrict__ G,
    const float* __restrict__ sq, int* __restrict__ near) {
  __shared__ unsigned long long wmin[4];
  const int i = blockIdx.x;
  const int t = threadIdx.x;
  const float sqi = sq[i];
  unsigned long long key[13];
#pragma unroll
  for (int e = 0; e < 13; ++e) {
    int j = t + (e << 8);
    float d2 = INFINITY;
    if (j < N_TOK) d2 = (sqi - 2.f * G[(size_t)i * N_TOK + j]) + sq[j];
    key[e] = ((unsigned long long)f2mono(d2) << 32) | (unsigned)j;
  }
  unsigned long long last = 0ull;
#pragma unroll 1
  for (int r = 0; r < 16; ++r) {
    unsigned long long best = ~0ull;
#pragma unroll
    for (int e = 0; e < 13; ++e) {
      bool ok = (key[e] > last) && (key[e] < best);
      best = ok ? key[e] : best;
    }
#pragma unroll
    for (int m = 1; m < 64; m <<= 1) {
      unsigned long long o = sx64(best, m);
      best = (o < best) ? o : best;
    }
    __syncthreads();
    if ((t & 63) == 0) wmin[t >> 6] = best;
    __syncthreads();
    unsigned long long b0 = wmin[0] < wmin[1] ? wmin[0] : wmin[1];
    unsigned long long b1 = wmin[2] < wmin[3] ? wmin[2] : wmin[3];
    best = b0 < b1 ? b0 : b1;
    if (t == 0) atomicAdd(&near[(unsigned)(best & 0xffffffffu)], 1);
    last = best;
  }
}

// ------------------------------------------------------------- max(near)
__global__ __launch_bounds__(256) void nearmax_k(const int* __restrict__ near,
                                                 int* __restrict__ nmax) {
  __shared__ int sm[4];
  const int t = threadIdx.x;
  int m = 0;
  for (int j = t; j < N_TOK; j += 256) m = max(m, near[j]);
#pragma unroll
  for (int s = 1; s < 64; s <<= 1) m = max(m, __shfl_xor(m, s, 64));
  if ((t & 63) == 0) sm[t >> 6] = m;
  __syncthreads();
  if (t == 0) nmax[0] = max(max(sm[0], sm[1]), max(sm[2], sm[3]));
}

// ------------------------------------------------ qk_in = x + emb[ni(near)]
__global__ __launch_bounds__(256) void qkin_k(const float* __restrict__ x,
    const int* __restrict__ near, const int* __restrict__ nmax,
    const float* __restrict__ emb, float* __restrict__ qkin) {
  const int i = blockIdx.x, t = threadIdx.x;
  const float nf = (float)near[i], mf = (float)nmax[0];
  const int ni = (int)(nf / mf * 9.0f);
  qkin[(size_t)i * CD + t] = x[(size_t)i * CD + t] + emb[ni * CD + t];
}

// ----------------------------------------- flash attention, bf16 MFMA
// grid (49, 8): 64 queries x 1 head per block; 4 waves, 16 queries/wave.
// MFMA 16x16x32: D[row=(l>>4)*4+r][col=l&15].
__global__ __launch_bounds__(256) void attn_mfma_k(const float* __restrict__ Qm,
    const float* __restrict__ Km, const float* __restrict__ Vm,
    const float* __restrict__ gp, float* __restrict__ Om) {
  __shared__ __align__(16) short Ks[64][40];      // K rows [j][d], 80B stride
  __shared__ __align__(16) short Vt[32][72];      // V^T [d][j], 144B stride
  __shared__ __align__(16) short Pl[4][16][72];   // per-wave P [i][j]
  __shared__ float gpj[64];
  const int h = blockIdx.y;
  const int i0 = blockIdx.x * 64;
  const int t = threadIdx.x;
  const int w = t >> 6, l = t & 63;
  const int g = l >> 4, c = l & 15;
  const int sr = t >> 2, seg = t & 3;             // staging row/segment
  const int iw = i0 + w * 16;                     // wave's query base

  // Q fragment (A-operand): lane holds Q[iw+c][g*8 .. +8] * SCALE
  short8v qfrag;
  {
    const float* qp = &Qm[(size_t)(iw + c) * CD + h * DH + g * 8];
    float4 q1 = *(const float4*)qp;
    float4 q2 = *(const float4*)(qp + 4);
    q1.x *= SCALE; q1.y *= SCALE; q1.z *= SCALE; q1.w *= SCALE;
    q2.x *= SCALE; q2.y *= SCALE; q2.z *= SCALE; q2.w *= SCALE;
    qfrag = cvt8(q1, q2);
  }
  float gpi[4];
#pragma unroll
  for (int r = 0; r < 4; ++r)
    gpi[r] = gp[(size_t)(iw + g * 4 + r) * NHD + h];

  float mrun[4] = {-INFINITY, -INFINITY, -INFINITY, -INFINITY};
  float lrun[4] = {0.f, 0.f, 0.f, 0.f};
  f32x4 oacc[2] = {};
  const f32x4 zz = {0.f, 0.f, 0.f, 0.f};

  for (int j0 = 0; j0 < N_TOK; j0 += 64) {
    // ---- stage K tile, V^T tile, gpj
    const float* kp = &Km[(size_t)(j0 + sr) * CD + h * DH + seg * 8];
    const float4 k1 = *(const float4*)kp;
    const float4 k2 = *(const float4*)(kp + 4);
    const float* vp = &Vm[(size_t)(j0 + sr) * CD + h * DH + seg * 8];
    const float4 v1 = *(const float4*)vp;
    const float4 v2 = *(const float4*)(vp + 4);
    float gj = 0.f;
    if (t < 64) gj = gp[(size_t)(j0 + t) * NHD + h];
    __syncthreads();   // previous tile's compute done before overwrite
    *(short8v*)&Ks[sr][seg * 8] = cvt8(k1, k2);
    {
      const float vv[8] = {v1.x, v1.y, v1.z, v1.w, v2.x, v2.y, v2.z, v2.w};
#pragma unroll
      for (int u = 0; u < 8; ++u) Vt[seg * 8 + u][sr] = bfr(vv[u]);
    }
    if (t < 64) gpj[t] = gj;
    __syncthreads();

    // ---- QK^T: 4 MFMAs (one per 16-j subtile), K=32 = full head dim
    f32x4 sacc[4];
#pragma unroll
    for (int sub = 0; sub < 4; ++sub) {
      const short8v kf = *(const short8v*)&Ks[sub * 16 + c][g * 8];
      sacc[sub] = __builtin_amdgcn_mfma_f32_16x16x32_bf16(qfrag, kf, zz, 0, 0, 0);
    }
    // ---- bias + online softmax (row i = g*4+r, col j = sub*16+c)
    float s[4][4];
    float gjc[4];
#pragma unroll
    for (int sub = 0; sub < 4; ++sub) gjc[sub] = gpj[sub * 16 + c];
#pragma unroll
    for (int sub = 0; sub < 4; ++sub)
#pragma unroll
      for (int r = 0; r < 4; ++r)
        s[sub][r] = sacc[sub][r] + fabsf(gpi[r] - gjc[sub]);
#pragma unroll
    for (int r = 0; r < 4; ++r) {
      float mx = fmaxf(fmaxf(s[0][r], s[1][r]), fmaxf(s[2][r], s[3][r]));
      mx = fmaxf(mx, __shfl_xor(mx, 1, 64));
      mx = fmaxf(mx, __shfl_xor(mx, 2, 64));
      mx = fmaxf(mx, __shfl_xor(mx, 4, 64));
      mx = fmaxf(mx, __shfl_xor(mx, 8, 64));
      const float mn = fmaxf(mrun[r], mx);
      const float cr = __expf(mrun[r] - mn);
      mrun[r] = mn;
      float ps = 0.f;
#pragma unroll
      for (int sub = 0; sub < 4; ++sub) {
        const float p = __expf(s[sub][r] - mn);
        Pl[w][g * 4 + r][sub * 16 + c] = bfr(p);
        ps += p;
      }
      ps += __shfl_xor(ps, 1, 64);
      ps += __shfl_xor(ps, 2, 64);
      ps += __shfl_xor(ps, 4, 64);
      ps += __shfl_xor(ps, 8, 64);
      lrun[r] = lrun[r] * cr + ps;
      oacc[0][r] *= cr;
      oacc[1][r] *= cr;
    }
    // ---- PV: O[i][d] += P[i][j] V[j][d]; 2 j-chunks x 2 d-subtiles
#pragma unroll
    for (int chunk = 0; chunk < 2; ++chunk) {
      const short8v pf = *(const short8v*)&Pl[w][c][chunk * 32 + g * 8];
#pragma unroll
      for (int ds = 0; ds < 2; ++ds) {
        const short8v vf = *(const short8v*)&Vt[ds * 16 + c][chunk * 32 + g * 8];
        oacc[ds] = __builtin_amdgcn_mfma_f32_16x16x32_bf16(pf, vf, oacc[ds], 0, 0, 0);
      }
    }
  }
#pragma unroll
  for (int r = 0; r < 4; ++r) {
    const float inv = 1.f / lrun[r];
    const size_t row = (size_t)(iw + g * 4 + r) * CD + h * DH;
    Om[row + c] = oacc[0][r] * inv;
    Om[row + 16 + c] = oacc[1][r] * inv;
  }
}

// -------------------------------------------------- LayerNorm (+residual)
__global__ __launch_bounds__(256) void ln_k(const float* __restrict__ xin,
    const float* __restrict__ add, const float* __restrict__ g,
    const float* __restrict__ b, float* __restrict__ xout) {
  __shared__ float red1[4];
  __shared__ float red2[4];
  const int i = blockIdx.x, t = threadIdx.x;
  float v = xin[(size_t)i * CD + t];
  if (add) v += add[(size_t)i * CD + t];
  float s = v;
#pragma unroll
  for (int m = 1; m < 64; m <<= 1) s += __shfl_xor(s, m, 64);
  if ((t & 63) == 0) red1[t >> 6] = s;
  __syncthreads();
  const float mean = (red1[0] + red1[1] + red1[2] + red1[3]) * (1.f / 256.f);
  const float d = v - mean;
  float s2 = d * d;
#pragma unroll
  for (int m = 1; m < 64; m <<= 1) s2 += __shfl_xor(s2, m, 64);
  if ((t & 63) == 0) red2[t >> 6] = s2;
  __syncthreads();
  const float var = (red2[0] + red2[1] + red2[2] + red2[3]) * (1.f / 256.f);
  xout[(size_t)i * CD + t] = d * rsqrtf(var + 1e-5f) * g[t] + b[t];
}

// ---------------------------------------------------------------- launch
extern "C" void kernel_launch(void* const* d_in, const int* in_sizes, int n_in,
                              void* d_out, int out_size, void* d_ws, size_t ws_size,
                              hipStream_t stream) {
  const float* src  = (const float*)d_in[0];
  const float* c1w  = (const float*)d_in[1];
  const float* c1b  = (const float*)d_in[2];
  const float* c2w  = (const float*)d_in[3];
  const float* c2b  = (const float*)d_in[4];
  const float* nemb = (const float*)d_in[5];
  const float* Wq   = (const float*)d_in[6];
  const float* bq   = (const float*)d_in[7];
  const float* Wk   = (const float*)d_in[8];
  const float* bk   = (const float*)d_in[9];
  const float* Wv   = (const float*)d_in[10];
  const float* bv   = (const float*)d_in[11];
  const float* Wo   = (const float*)d_in[12];
  const float* bo   = (const float*)d_in[13];
  const float* W1   = (const float*)d_in[14];
  const float* b1   = (const float*)d_in[15];
  const float* W2   = (const float*)d_in[16];
  const float* b2   = (const float*)d_in[17];
  const float* ln1g = (const float*)d_in[18];
  const float* ln1b = (const float*)d_in[19];
  const float* ln2g = (const float*)d_in[20];
  const float* ln2b = (const float*)d_in[21];
  const float* ng   = (const float*)d_in[22];
  const float* nb   = (const float*)d_in[23];

  float* ws = (float*)d_ws;
  const size_t NC = (size_t)N_TOK * CD;
  float* X    = ws;
  float* QKIN = X + NC;
  float* QB   = QKIN + NC;
  float* KB   = QB + NC;
  float* VB   = KB + NC;
  float* O1   = VB + NC;
  float* TMP  = O1 + NC;
  float* FF1  = TMP + NC;                        // 3136*1024
  float* G    = FF1 + (size_t)N_TOK * DFFD;      // 3136*3136 (also im2col)
  float* T1   = G + (size_t)N_TOK * N_TOK;       // 3136*128
  float* GP   = T1 + (size_t)N_TOK * 128;        // 3136*8
  float* SQF  = GP + (size_t)N_TOK * NHD;        // 3136
  int*   NEAR = (int*)(SQF + N_TOK);             // 3136 ints
  int*   NMAX = NEAR + N_TOK;                    // 1 int

  // conv positional encoder: im2col + bf16 gemm(relu) + conv2(sigmoid)
  im2col_k<<<28224, 256, 0, stream>>>(src, G);
  gemm_bt_bf16<1><<<dim3(2, 49), 256, 0, stream>>>(G, c1w, c1b, T1, N_TOK, 128, 2304);
  conv2_k<<<98, 256, 0, stream>>>(T1, c2w, c2b, GP);
  transpose_k<<<dim3(98, 8), 256, 0, stream>>>(src, X, 256, N_TOK);

  for (int l = 0; l < 4; ++l) {
    // ---- kNN graph (fp32, symmetric triangle) -> near counts
    rowsq_k<<<N_TOK, 64, 0, stream>>>(X, SQF);
    gemm_syr_k<<<1225, 256, 0, stream>>>(X, G, N_TOK, CD);
    hipMemsetAsync(NEAR, 0, N_TOK * sizeof(int), stream);
    topk_k<<<N_TOK, 256, 0, stream>>>(G, SQF, NEAR);
    nearmax_k<<<1, 256, 0, stream>>>(NEAR, NMAX);
    qkin_k<<<N_TOK, 256, 0, stream>>>(X, NEAR, NMAX, nemb, QKIN);
    // ---- attention (bf16 MFMA)
    gemm_bt_bf16<0><<<dim3(4, 49), 256, 0, stream>>>(QKIN, Wq + (size_t)l * 65536, bq + l * 256, QB, N_TOK, CD, CD);
    gemm_bt_bf16<0><<<dim3(4, 49), 256, 0, stream>>>(QKIN, Wk + (size_t)l * 65536, bk + l * 256, KB, N_TOK, CD, CD);
    gemm_bt_bf16<0><<<dim3(4, 49), 256, 0, stream>>>(X,    Wv + (size_t)l * 65536, bv + l * 256, VB, N_TOK, CD, CD);
    attn_mfma_k<<<dim3(49, 8), 256, 0, stream>>>(QB, KB, VB, GP, O1);
    gemm_bt_bf16<0><<<dim3(4, 49), 256, 0, stream>>>(O1, Wo + (size_t)l * 65536, bo + l * 256, TMP, N_TOK, CD, CD);
    ln_k<<<N_TOK, 256, 0, stream>>>(X, TMP, ln1g + l * 256, ln1b + l * 256, X);
    // ---- FFN (bf16 MFMA)
    gemm_bt_bf16<1><<<dim3(16, 49), 256, 0, stream>>>(X, W1 + (size_t)l * 262144, b1 + l * 1024, FF1, N_TOK, DFFD, CD);
    gemm_bt_bf16<0><<<dim3(4, 49), 256, 0, stream>>>(FF1, W2 + (size_t)l * 262144, b2 + l * 256, TMP, N_TOK, CD, DFFD);
    ln_k<<<N_TOK, 256, 0, stream>>>(X, TMP, ln2g + l * 256, ln2b + l * 256, X);
  }
  // final LN + transpose to [1,C,H,W]
  ln_k<<<N_TOK, 256, 0, stream>>>(X, nullptr, ng, nb, TMP);
  transpose_k<<<dim3(8, 98), 256, 0, stream>>>(TMP, (float*)d_out, N_TOK, 256);
}

// Round 4
// 1214.263 us; speedup vs baseline: 2.1297x; 1.0591x over previous
//
#include <hip/hip_runtime.h>
#include <math.h>

#define N_TOK 3136
#define CD    256
#define NHD   8
#define DH    32
#define DFFD  1024
#define SCALE 0.17677669529663687f  /* 32^-0.5 */

typedef __attribute__((ext_vector_type(8))) short short8v;
typedef __attribute__((ext_vector_type(4))) float f32x4;

// ---------------------------------------------------------------- utils
__device__ __forceinline__ unsigned long long sx64(unsigned long long v, int m) {
  unsigned lo = (unsigned)__shfl_xor((int)(unsigned)(v & 0xffffffffull), m, 64);
  unsigned hi = (unsigned)__shfl_xor((int)(unsigned)(v >> 32), m, 64);
  return ((unsigned long long)hi << 32) | lo;
}

__device__ __forceinline__ unsigned f2mono(float v) {
  unsigned b = __float_as_uint(v);
  return (b & 0x80000000u) ? ~b : (b | 0x80000000u);
}

// fp32 -> bf16 round-to-nearest-even
__device__ __forceinline__ short bfr(float f) {
  unsigned u = __float_as_uint(f);
  unsigned r = (u + 0x7fffu + ((u >> 16) & 1u)) >> 16;
  return (short)r;
}

__device__ __forceinline__ short8v cvt8(float4 a, float4 b) {
  short8v r;
  r[0] = bfr(a.x); r[1] = bfr(a.y); r[2] = bfr(a.z); r[3] = bfr(a.w);
  r[4] = bfr(b.x); r[5] = bfr(b.y); r[6] = bfr(b.z); r[7] = bfr(b.w);
  return r;
}

// split fp32 into bf16 hi (truncate) + bf16 lo (truncate of remainder)
__device__ __forceinline__ void split8(float4 a, float4 b, short8v& hi, short8v& lo) {
  const float f[8] = {a.x, a.y, a.z, a.w, b.x, b.y, b.z, b.w};
#pragma unroll
  for (int u = 0; u < 8; ++u) {
    const unsigned ui = __float_as_uint(f[u]);
    hi[u] = (short)(ui >> 16);
    const float hf = __uint_as_float(ui & 0xffff0000u);
    lo[u] = (short)(__float_as_uint(f[u] - hf) >> 16);
  }
}

// ------------------------------------------------- transpose (32x32 tiles)
__global__ __launch_bounds__(256) void transpose_k(const float* __restrict__ in,
    float* __restrict__ out, int R, int C) {
  __shared__ float ls[32][33];
  const int c0 = blockIdx.x * 32, r0 = blockIdx.y * 32;
  const int tx = threadIdx.x & 31, ty = threadIdx.x >> 5;
#pragma unroll
  for (int j = 0; j < 4; ++j) {
    int r = ty + j * 8;
    ls[r][tx] = in[(size_t)(r0 + r) * C + c0 + tx];
  }
  __syncthreads();
#pragma unroll
  for (int j = 0; j < 4; ++j) {
    int cc = ty + j * 8;
    out[(size_t)(c0 + cc) * R + r0 + tx] = ls[tx][cc];
  }
}

// ------------------------------------------------------------- im2col 3x3
__global__ __launch_bounds__(256) void im2col_k(const float* __restrict__ src,
    float* __restrict__ col) {
  int e = blockIdx.x * 256 + threadIdx.x;
  int pix = e / 2304;
  int kk = e - pix * 2304;
  int ci = kk / 9;
  int r = kk - ci * 9;
  int ky = r / 3, kx = r - ky * 3;
  int y = pix / 56, x = pix - y * 56;
  int yy = y + ky - 1, xx = x + kx - 1;
  float v = (yy >= 0 && yy < 56 && xx >= 0 && xx < 56)
                ? src[(size_t)ci * 3136 + yy * 56 + xx] : 0.f;
  col[(size_t)e] = v;
}

// ------------------------------------------ bf16 MFMA GEMM NT (fp32 in)
// OMODE: 0 fp32 C[m][n]; 1 bf16 C[m][n]*SCALE; 2 bf16 C[m][n]; 3 bf16 C^T[n][m]
template <int RELU, int OMODE>
__global__ __launch_bounds__(256) void gemm_bt_bf16(const float* __restrict__ A,
    const float* __restrict__ B, const float* __restrict__ bias,
    void* __restrict__ Cv, int M, int N, int K) {
  __shared__ __align__(16) short As[64][40];
  __shared__ __align__(16) short Bs[64][40];
  const int n0 = blockIdx.x * 64;
  const int m0 = blockIdx.y * 64;
  const int t = threadIdx.x;
  const int w = t >> 6, l = t & 63;
  const int g = l >> 4, c = l & 15;
  const int wr = w >> 1, wc = w & 1;
  const int sr = t >> 2, seg = t & 3;
  const float* Ap = A + (size_t)(m0 + sr) * K + seg * 8;
  const float* Bp = B + (size_t)(n0 + sr) * K + seg * 8;
  f32x4 acc[2][2] = {};
  for (int k0 = 0; k0 < K; k0 += 32) {
    const float4 a1 = *(const float4*)(Ap + k0);
    const float4 a2 = *(const float4*)(Ap + k0 + 4);
    const float4 b1 = *(const float4*)(Bp + k0);
    const float4 b2 = *(const float4*)(Bp + k0 + 4);
    __syncthreads();
    *(short8v*)&As[sr][seg * 8] = cvt8(a1, a2);
    *(short8v*)&Bs[sr][seg * 8] = cvt8(b1, b2);
    __syncthreads();
    short8v af[2], bf[2];
#pragma unroll
    for (int mi = 0; mi < 2; ++mi)
      af[mi] = *(const short8v*)&As[wr * 32 + mi * 16 + c][g * 8];
#pragma unroll
    for (int ni = 0; ni < 2; ++ni)
      bf[ni] = *(const short8v*)&Bs[wc * 32 + ni * 16 + c][g * 8];
#pragma unroll
    for (int mi = 0; mi < 2; ++mi)
#pragma unroll
      for (int ni = 0; ni < 2; ++ni)
        acc[mi][ni] = __builtin_amdgcn_mfma_f32_16x16x32_bf16(
            af[mi], bf[ni], acc[mi][ni], 0, 0, 0);
  }
  float* Cf = (float*)Cv;
  short* Ct = (short*)Cv;
#pragma unroll
  for (int mi = 0; mi < 2; ++mi) {
#pragma unroll
    for (int ni = 0; ni < 2; ++ni) {
      const int col = n0 + wc * 32 + ni * 16 + c;
      const float bb = bias ? bias[col] : 0.f;
      if (OMODE == 3) {
        const int mb = m0 + wr * 32 + mi * 16 + g * 4;
        uint2 pk;
        float v0 = acc[mi][ni][0] + bb, v1 = acc[mi][ni][1] + bb;
        float v2 = acc[mi][ni][2] + bb, v3 = acc[mi][ni][3] + bb;
        pk.x = (unsigned)(unsigned short)bfr(v0) | ((unsigned)(unsigned short)bfr(v1) << 16);
        pk.y = (unsigned)(unsigned short)bfr(v2) | ((unsigned)(unsigned short)bfr(v3) << 16);
        *(uint2*)&Ct[(size_t)col * M + mb] = pk;
      } else {
#pragma unroll
        for (int q = 0; q < 4; ++q) {
          const int m = m0 + wr * 32 + mi * 16 + g * 4 + q;
          float v = acc[mi][ni][q] + bb;
          if (RELU) v = fmaxf(v, 0.f);
          if (OMODE == 0) Cf[(size_t)m * N + col] = v;
          else if (OMODE == 1) Ct[(size_t)m * N + col] = bfr(v * SCALE);
          else if (OMODE == 2) Ct[(size_t)m * N + col] = bfr(v);
        }
      }
    }
  }
}

// ------------------------- Gram G = X X^T via split-bf16 (hi+lo) MFMA
// Upper-triangle 64x64 blocks (1225); ~2^-16 relative accuracy.
__global__ __launch_bounds__(256) void gemm_syr2_k(const float* __restrict__ A,
    float* __restrict__ C) {
  __shared__ __align__(16) short AsH[64][40];
  __shared__ __align__(16) short AsL[64][40];
  __shared__ __align__(16) short BsH[64][40];
  __shared__ __align__(16) short BsL[64][40];
  int bid = blockIdx.x;
  int bi = (int)((sqrtf(8.f * (float)bid + 1.f) - 1.f) * 0.5f);
  while ((bi + 1) * (bi + 2) / 2 <= bid) ++bi;
  while (bi * (bi + 1) / 2 > bid) --bi;
  const int bj = bid - bi * (bi + 1) / 2;
  const int m0 = bi * 64, n0 = bj * 64;
  const int t = threadIdx.x;
  const int w = t >> 6, l = t & 63;
  const int g = l >> 4, c = l & 15;
  const int wr = w >> 1, wc = w & 1;
  const int sr = t >> 2, seg = t & 3;
  const float* Ap = A + (size_t)(m0 + sr) * CD + seg * 8;
  const float* Bp = A + (size_t)(n0 + sr) * CD + seg * 8;
  f32x4 acc[2][2] = {};
  for (int k0 = 0; k0 < CD; k0 += 32) {
    const float4 a1 = *(const float4*)(Ap + k0);
    const float4 a2 = *(const float4*)(Ap + k0 + 4);
    const float4 b1 = *(const float4*)(Bp + k0);
    const float4 b2 = *(const float4*)(Bp + k0 + 4);
    __syncthreads();
    short8v h8, l8;
    split8(a1, a2, h8, l8);
    *(short8v*)&AsH[sr][seg * 8] = h8;
    *(short8v*)&AsL[sr][seg * 8] = l8;
    split8(b1, b2, h8, l8);
    *(short8v*)&BsH[sr][seg * 8] = h8;
    *(short8v*)&BsL[sr][seg * 8] = l8;
    __syncthreads();
    short8v afH[2], afL[2], bfH[2], bfL[2];
#pragma unroll
    for (int mi = 0; mi < 2; ++mi) {
      afH[mi] = *(const short8v*)&AsH[wr * 32 + mi * 16 + c][g * 8];
      afL[mi] = *(const short8v*)&AsL[wr * 32 + mi * 16 + c][g * 8];
    }
#pragma unroll
    for (int ni = 0; ni < 2; ++ni) {
      bfH[ni] = *(const short8v*)&BsH[wc * 32 + ni * 16 + c][g * 8];
      bfL[ni] = *(const short8v*)&BsL[wc * 32 + ni * 16 + c][g * 8];
    }
#pragma unroll
    for (int mi = 0; mi < 2; ++mi)
#pragma unroll
      for (int ni = 0; ni < 2; ++ni) {
        acc[mi][ni] = __builtin_amdgcn_mfma_f32_16x16x32_bf16(afH[mi], bfH[ni], acc[mi][ni], 0, 0, 0);
        acc[mi][ni] = __builtin_amdgcn_mfma_f32_16x16x32_bf16(afH[mi], bfL[ni], acc[mi][ni], 0, 0, 0);
        acc[mi][ni] = __builtin_amdgcn_mfma_f32_16x16x32_bf16(afL[mi], bfH[ni], acc[mi][ni], 0, 0, 0);
      }
  }
#pragma unroll
  for (int mi = 0; mi < 2; ++mi)
#pragma unroll
    for (int ni = 0; ni < 2; ++ni) {
      const int col = n0 + wc * 32 + ni * 16 + c;
#pragma unroll
      for (int q = 0; q < 4; ++q) {
        const int m = m0 + wr * 32 + mi * 16 + g * 4 + q;
        const float v = acc[mi][ni][q];
        C[(size_t)m * N_TOK + col] = v;
        C[(size_t)col * N_TOK + m] = v;
      }
    }
}

// ------------------------------------------------------------ conv2 (8ch)
__global__ __launch_bounds__(256) void conv2_k(const float* __restrict__ t1,
    const float* __restrict__ w, const float* __restrict__ b,
    float* __restrict__ gp) {
  __shared__ float ws3[9 * 8 * 132];
  const int t = threadIdx.x;
  for (int e = t; e < 9216; e += 256) {
    int r = e >> 10;
    int rem = e & 1023;
    int co = rem >> 7;
    int ci = rem & 127;
    ws3[(r * 8 + co) * 132 + ci] = w[((size_t)co * 128 + ci) * 9 + r];
  }
  __syncthreads();
  const int pix = blockIdx.x * 32 + (t >> 3);
  const int co = t & 7;
  const int y = pix / 56, x = pix - y * 56;
  float acc = b[co];
  for (int ky = 0; ky < 3; ++ky) {
    int yy = y + ky - 1;
    if (yy < 0 || yy >= 56) continue;
    for (int kx = 0; kx < 3; ++kx) {
      int xx = x + kx - 1;
      if (xx < 0 || xx >= 56) continue;
      const float4* tp = (const float4*)&t1[(size_t)(yy * 56 + xx) * 128];
      const float* wp = &ws3[((ky * 3 + kx) * 8 + co) * 132];
#pragma unroll
      for (int c4 = 0; c4 < 32; ++c4) {
        const float4 tv = tp[c4];
        const float4 wv = *(const float4*)&wp[c4 * 4];
        acc += tv.x * wv.x + tv.y * wv.y + tv.z * wv.z + tv.w * wv.w;
      }
    }
  }
  gp[pix * 8 + co] = 1.f / (1.f + expf(-acc));
}

// ------------------------------------------------------------- row ||x||^2
__global__ __launch_bounds__(64) void rowsq_k(const float* __restrict__ x,
                                              float* __restrict__ sq) {
  const int i = blockIdx.x, lane = threadIdx.x;
  const float4 v = ((const float4*)&x[(size_t)i * CD])[lane];
  float s = v.x * v.x + v.y * v.y + v.z * v.z + v.w * v.w;
#pragma unroll
  for (int m = 1; m < 64; m <<= 1) s += __shfl_xor(s, m, 64);
  if (lane == 0) sq[i] = s;
}

// -------------------------------------------------- top-16 NN + in-degree
__global__ __launch_bounds__(256) void topk_k(const float* __restrict__ G,
    const float* __restrict__ sq, int* __restrict__ near) {
  __shared__ unsigned long long wmin[4];
  const int i = blockIdx.x;
  const int t = threadIdx.x;
  const float sqi = sq[i];
  unsigned long long key[13];
#pragma unroll
  for (int e = 0; e < 13; ++e) {
    int j = t + (e << 8);
    float d2 = INFINITY;
    if (j < N_TOK) d2 = (sqi - 2.f * G[(size_t)i * N_TOK + j]) + sq[j];
    key[e] = ((unsigned long long)f2mono(d2) << 32) | (unsigned)j;
  }
  unsigned long long last = 0ull;
#pragma unroll 1
  for (int r = 0; r < 16; ++r) {
    unsigned long long best = ~0ull;
#pragma unroll
    for (int e = 0; e < 13; ++e) {
      bool ok = (key[e] > last) && (key[e] < best);
      best = ok ? key[e] : best;
    }
#pragma unroll
    for (int m = 1; m < 64; m <<= 1) {
      unsigned long long o = sx64(best, m);
      best = (o < best) ? o : best;
    }
    __syncthreads();
    if ((t & 63) == 0) wmin[t >> 6] = best;
    __syncthreads();
    unsigned long long b0 = wmin[0] < wmin[1] ? wmin[0] : wmin[1];
    unsigned long long b1 = wmin[2] < wmin[3] ? wmin[2] : wmin[3];
    best = b0 < b1 ? b0 : b1;
    if (t == 0) atomicAdd(&near[(unsigned)(best & 0xffffffffu)], 1);
    last = best;
  }
}

// ------------------------------------------------------------- max(near)
__global__ __launch_bounds__(256) void nearmax_k(const int* __restrict__ near,
                                                 int* __restrict__ nmax) {
  __shared__ int sm[4];
  const int t = threadIdx.x;
  int m = 0;
  for (int j = t; j < N_TOK; j += 256) m = max(m, near[j]);
#pragma unroll
  for (int s = 1; s < 64; s <<= 1) m = max(m, __shfl_xor(m, s, 64));
  if ((t & 63) == 0) sm[t >> 6] = m;
  __syncthreads();
  if (t == 0) nmax[0] = max(max(sm[0], sm[1]), max(sm[2], sm[3]));
}

// ------------------------------------------------ qk_in = x + emb[ni(near)]
__global__ __launch_bounds__(256) void qkin_k(const float* __restrict__ x,
    const int* __restrict__ near, const int* __restrict__ nmax,
    const float* __restrict__ emb, float* __restrict__ qkin) {
  const int i = blockIdx.x, t = threadIdx.x;
  const float nf = (float)near[i], mf = (float)nmax[0];
  const int ni = (int)(nf / mf * 9.0f);
  qkin[(size_t)i * CD + t] = x[(size_t)i * CD + t] + emb[ni * CD + t];
}

// ------------------------------------------------ gp [tok][8] -> gpT [8][tok]
__global__ __launch_bounds__(256) void gpt_k(const float* __restrict__ gp,
                                             float* __restrict__ gpT) {
  const int e = blockIdx.x * 256 + threadIdx.x;
  const int i = e >> 3, h = e & 7;
  gpT[h * N_TOK + i] = gp[e];
}

// ---------------------------- flash attention v3: barrier-free, global frags
// grid (49, 8, 2): 4 waves/block, each wave = 16 queries; z = j-split half.
// Swapped QK^T (mfma(K,Q)): lane owns one query's softmax state.
__global__ __launch_bounds__(256) void attn_v3_k(const short* __restrict__ Qb,
    const short* __restrict__ Kb, const short* __restrict__ Vt,
    const float* __restrict__ gpT, float* __restrict__ OP,
    float* __restrict__ ML) {
  __shared__ __align__(16) short Pl[4][16][80];
  const int h = blockIdx.y, sp = blockIdx.z;
  const int t = threadIdx.x;
  const int w = t >> 6, l = t & 63;
  const int g = l >> 4, c = l & 15;
  const int iw = (blockIdx.x * 4 + w) * 16;
  const size_t hoff = (size_t)h * DH;
  const short8v qf = *(const short8v*)&Qb[(size_t)(iw + c) * CD + hoff + g * 8];
  const float gpi = gpT[h * N_TOK + iw + c];
  const int jt0 = sp ? 25 : 0, jt1 = sp ? 49 : 25;
  float mrun = -INFINITY, lrun = 0.f;
  f32x4 oacc[2] = {};
  const f32x4 zz = {0.f, 0.f, 0.f, 0.f};

  short8v kf[4];
#pragma unroll
  for (int sub = 0; sub < 4; ++sub)
    kf[sub] = *(const short8v*)&Kb[(size_t)(jt0 * 64 + sub * 16 + c) * CD + hoff + g * 8];

  for (int jt = jt0; jt < jt1; ++jt) {
    const int j0 = jt * 64;
    // QK^T swapped: sacc[sub][q] = S[j0+sub*16+g*4+q][iw+c]
    f32x4 sacc[4];
#pragma unroll
    for (int sub = 0; sub < 4; ++sub)
      sacc[sub] = __builtin_amdgcn_mfma_f32_16x16x32_bf16(kf[sub], qf, zz, 0, 0, 0);
    // prefetch next K tile
    if (jt + 1 < jt1) {
#pragma unroll
      for (int sub = 0; sub < 4; ++sub)
        kf[sub] = *(const short8v*)&Kb[(size_t)(j0 + 64 + sub * 16 + c) * CD + hoff + g * 8];
    }
    // V^T fragments for this tile (independent -> issued early)
    short8v vf[2][2];
#pragma unroll
    for (int ch = 0; ch < 2; ++ch)
#pragma unroll
      for (int ds = 0; ds < 2; ++ds)
        vf[ch][ds] = *(const short8v*)&Vt[(hoff + ds * 16 + c) * (size_t)N_TOK + j0 + ch * 32 + g * 8];
    float4 gj[4];
#pragma unroll
    for (int sub = 0; sub < 4; ++sub)
      gj[sub] = *(const float4*)&gpT[h * N_TOK + j0 + sub * 16 + g * 4];
    // bias + per-query (lane-local) softmax over 16 in-lane j's
    float sv[16];
#pragma unroll
    for (int sub = 0; sub < 4; ++sub) {
      sv[sub * 4 + 0] = sacc[sub][0] + fabsf(gpi - gj[sub].x);
      sv[sub * 4 + 1] = sacc[sub][1] + fabsf(gpi - gj[sub].y);
      sv[sub * 4 + 2] = sacc[sub][2] + fabsf(gpi - gj[sub].z);
      sv[sub * 4 + 3] = sacc[sub][3] + fabsf(gpi - gj[sub].w);
    }
    float mx = sv[0];
#pragma unroll
    for (int e = 1; e < 16; ++e) mx = fmaxf(mx, sv[e]);
    mx = fmaxf(mx, __shfl_xor(mx, 16, 64));
    mx = fmaxf(mx, __shfl_xor(mx, 32, 64));
    const float mn = fmaxf(mrun, mx);
    const float cr = __expf(mrun - mn);
    mrun = mn;
    float pv[16], ps = 0.f;
#pragma unroll
    for (int e = 0; e < 16; ++e) { pv[e] = __expf(sv[e] - mn); ps += pv[e]; }
    ps += __shfl_xor(ps, 16, 64);
    ps += __shfl_xor(ps, 32, 64);
    lrun = lrun * cr + ps;
    // rescale O rows (row q belongs to query g*4+q; its cr lives in lane g*4+q)
    float crq[4];
#pragma unroll
    for (int q = 0; q < 4; ++q) crq[q] = __shfl(cr, g * 4 + q, 64);
#pragma unroll
    for (int q = 0; q < 4; ++q) { oacc[0][q] *= crq[q]; oacc[1][q] *= crq[q]; }
    // pack P (bf16) to per-wave LDS: Pl[w][i=c][j]
#pragma unroll
    for (int sub = 0; sub < 4; ++sub) {
      uint2 pk;
      pk.x = (unsigned)(unsigned short)bfr(pv[sub * 4 + 0]) |
             ((unsigned)(unsigned short)bfr(pv[sub * 4 + 1]) << 16);
      pk.y = (unsigned)(unsigned short)bfr(pv[sub * 4 + 2]) |
             ((unsigned)(unsigned short)bfr(pv[sub * 4 + 3]) << 16);
      *(uint2*)&Pl[w][c][sub * 16 + g * 4] = pk;
    }
    // PV: oacc[ds][q] = O[iw+g*4+q][ds*16+c]
#pragma unroll
    for (int ch = 0; ch < 2; ++ch) {
      const short8v pf = *(const short8v*)&Pl[w][c][ch * 32 + g * 8];
      oacc[0] = __builtin_amdgcn_mfma_f32_16x16x32_bf16(pf, vf[ch][0], oacc[0], 0, 0, 0);
      oacc[1] = __builtin_amdgcn_mfma_f32_16x16x32_bf16(pf, vf[ch][1], oacc[1], 0, 0, 0);
    }
  }
  const size_t ob = (size_t)(sp * 8 + h) * N_TOK + iw;
#pragma unroll
  for (int ds = 0; ds < 2; ++ds)
#pragma unroll
    for (int q = 0; q < 4; ++q)
      OP[(ob + g * 4 + q) * 32 + ds * 16 + c] = oacc[ds][q];
  if (l < 16) {
    ML[(ob + c) * 2 + 0] = mrun;
    ML[(ob + c) * 2 + 1] = lrun;
  }
}

// ---------------------------------------- combine the two j-split halves
__global__ __launch_bounds__(256) void attn_comb_k(const float* __restrict__ OP,
    const float* __restrict__ ML, float* __restrict__ O1) {
  const int i = blockIdx.x, t = threadIdx.x;
  const int h = t >> 5, d = t & 31;
  const size_t b0 = (size_t)h * N_TOK + i;
  const size_t b1 = (size_t)(8 + h) * N_TOK + i;
  const float m0 = ML[b0 * 2], l0 = ML[b0 * 2 + 1];
  const float m1 = ML[b1 * 2], l1 = ML[b1 * 2 + 1];
  const float M = fmaxf(m0, m1);
  const float w0 = __expf(m0 - M), w1 = __expf(m1 - M);
  const float num = w0 * OP[b0 * 32 + d] + w1 * OP[b1 * 32 + d];
  const float den = w0 * l0 + w1 * l1;
  O1[(size_t)i * CD + t] = num / den;
}

// -------------------------------------------------- LayerNorm (+residual)
__global__ __launch_bounds__(256) void ln_k(const float* __restrict__ xin,
    const float* __restrict__ add, const float* __restrict__ g,
    const float* __restrict__ b, float* __restrict__ xout) {
  __shared__ float red1[4];
  __shared__ float red2[4];
  const int i = blockIdx.x, t = threadIdx.x;
  float v = xin[(size_t)i * CD + t];
  if (add) v += add[(size_t)i * CD + t];
  float s = v;
#pragma unroll
  for (int m = 1; m < 64; m <<= 1) s += __shfl_xor(s, m, 64);
  if ((t & 63) == 0) red1[t >> 6] = s;
  __syncthreads();
  const float mean = (red1[0] + red1[1] + red1[2] + red1[3]) * (1.f / 256.f);
  const float d = v - mean;
  float s2 = d * d;
#pragma unroll
  for (int m = 1; m < 64; m <<= 1) s2 += __shfl_xor(s2, m, 64);
  if ((t & 63) == 0) red2[t >> 6] = s2;
  __syncthreads();
  const float var = (red2[0] + red2[1] + red2[2] + red2[3]) * (1.f / 256.f);
  xout[(size_t)i * CD + t] = d * rsqrtf(var + 1e-5f) * g[t] + b[t];
}

// ---------------------------------------------------------------- launch
extern "C" void kernel_launch(void* const* d_in, const int* in_sizes, int n_in,
                              void* d_out, int out_size, void* d_ws, size_t ws_size,
                              hipStream_t stream) {
  const float* src  = (const float*)d_in[0];
  const float* c1w  = (const float*)d_in[1];
  const float* c1b  = (const float*)d_in[2];
  const float* c2w  = (const float*)d_in[3];
  const float* c2b  = (const float*)d_in[4];
  const float* nemb = (const float*)d_in[5];
  const float* Wq   = (const float*)d_in[6];
  const float* bq   = (const float*)d_in[7];
  const float* Wk   = (const float*)d_in[8];
  const float* bk   = (const float*)d_in[9];
  const float* Wv   = (const float*)d_in[10];
  const float* bv   = (const float*)d_in[11];
  const float* Wo   = (const float*)d_in[12];
  const float* bo   = (const float*)d_in[13];
  const float* W1   = (const float*)d_in[14];
  const float* b1   = (const float*)d_in[15];
  const float* W2   = (const float*)d_in[16];
  const float* b2   = (const float*)d_in[17];
  const float* ln1g = (const float*)d_in[18];
  const float* ln1b = (const float*)d_in[19];
  const float* ln2g = (const float*)d_in[20];
  const float* ln2b = (const float*)d_in[21];
  const float* ng   = (const float*)d_in[22];
  const float* nb   = (const float*)d_in[23];

  float* ws = (float*)d_ws;
  const size_t NC = (size_t)N_TOK * CD;          // 802816
  float* X    = ws;
  float* QKIN = X + NC;
  float* O1   = QKIN + NC;
  float* TMP  = O1 + NC;
  float* FF1  = TMP + NC;                        // 3136*1024 (attn OP/ML aliased here)
  float* OP   = FF1;                             // 2*8*3136*32 = 1605632
  float* ML   = OP + (size_t)2 * 8 * N_TOK * 32; // 2*8*3136*2 = 100352
  float* G    = FF1 + (size_t)N_TOK * DFFD;      // 3136*3136 (also im2col)
  float* T1   = G + (size_t)N_TOK * N_TOK;       // 3136*128
  float* GP   = T1 + (size_t)N_TOK * 128;        // 3136*8
  float* GPT  = GP + (size_t)N_TOK * NHD;        // 3136*8
  float* SQF  = GPT + (size_t)N_TOK * NHD;       // 3136
  short* QB16 = (short*)(SQF + N_TOK);           // NC bf16 -> NC/2 floats
  short* KB16 = QB16 + NC;
  short* VT16 = KB16 + NC;
  int*   NEAR = (int*)(VT16 + NC);               // 3136 ints
  int*   NMAX = NEAR + N_TOK;                    // 1 int

  // conv positional encoder
  im2col_k<<<28224, 256, 0, stream>>>(src, G);
  gemm_bt_bf16<1, 0><<<dim3(2, 49), 256, 0, stream>>>(G, c1w, c1b, T1, N_TOK, 128, 2304);
  conv2_k<<<98, 256, 0, stream>>>(T1, c2w, c2b, GP);
  gpt_k<<<98, 256, 0, stream>>>(GP, GPT);
  transpose_k<<<dim3(98, 8), 256, 0, stream>>>(src, X, 256, N_TOK);

  for (int l = 0; l < 4; ++l) {
    // ---- kNN graph -> near counts (split-bf16 MFMA Gram, fp32-grade)
    rowsq_k<<<N_TOK, 64, 0, stream>>>(X, SQF);
    gemm_syr2_k<<<1225, 256, 0, stream>>>(X, G);
    hipMemsetAsync(NEAR, 0, N_TOK * sizeof(int), stream);
    topk_k<<<N_TOK, 256, 0, stream>>>(G, SQF, NEAR);
    nearmax_k<<<1, 256, 0, stream>>>(NEAR, NMAX);
    qkin_k<<<N_TOK, 256, 0, stream>>>(X, NEAR, NMAX, nemb, QKIN);
    // ---- projections: Q bf16 pre-scaled, K bf16, V^T bf16
    gemm_bt_bf16<0, 1><<<dim3(4, 49), 256, 0, stream>>>(QKIN, Wq + (size_t)l * 65536, bq + l * 256, QB16, N_TOK, CD, CD);
    gemm_bt_bf16<0, 2><<<dim3(4, 49), 256, 0, stream>>>(QKIN, Wk + (size_t)l * 65536, bk + l * 256, KB16, N_TOK, CD, CD);
    gemm_bt_bf16<0, 3><<<dim3(4, 49), 256, 0, stream>>>(X,    Wv + (size_t)l * 65536, bv + l * 256, VT16, N_TOK, CD, CD);
    // ---- attention (barrier-free, j-split=2) + combine
    attn_v3_k<<<dim3(49, 8, 2), 256, 0, stream>>>(QB16, KB16, VT16, GPT, OP, ML);
    attn_comb_k<<<N_TOK, 256, 0, stream>>>(OP, ML, O1);
    gemm_bt_bf16<0, 0><<<dim3(4, 49), 256, 0, stream>>>(O1, Wo + (size_t)l * 65536, bo + l * 256, TMP, N_TOK, CD, CD);
    ln_k<<<N_TOK, 256, 0, stream>>>(X, TMP, ln1g + l * 256, ln1b + l * 256, X);
    // ---- FFN
    gemm_bt_bf16<1, 0><<<dim3(16, 49), 256, 0, stream>>>(X, W1 + (size_t)l * 262144, b1 + l * 1024, FF1, N_TOK, DFFD, CD);
    gemm_bt_bf16<0, 0><<<dim3(4, 49), 256, 0, stream>>>(FF1, W2 + (size_t)l * 262144, b2 + l * 256, TMP, N_TOK, CD, DFFD);
    ln_k<<<N_TOK, 256, 0, stream>>>(X, TMP, ln2g + l * 256, ln2b + l * 256, X);
  }
  // final LN + transpose to [1,C,H,W]
  ln_k<<<N_TOK, 256, 0, stream>>>(X, nullptr, ng, nb, TMP);
  transpose_k<<<dim3(8, 98), 256, 0, stream>>>(TMP, (float*)d_out, N_TOK, 256);
}

// Round 6
// 1108.144 us; speedup vs baseline: 2.3336x; 1.0958x over previous
//
#include <hip/hip_runtime.h>
#include <math.h>

#define N_TOK 3136
#define CD    256
#define NHD   8
#define DH    32
#define DFFD  1024
#define SCALE 0.17677669529663687f  /* 32^-0.5 */
#define LOG2E 1.4426950408889634f
#define QSC   (SCALE * LOG2E)

typedef __attribute__((ext_vector_type(8))) short short8v;
typedef __attribute__((ext_vector_type(4))) float f32x4;

// ---------------------------------------------------------------- utils
__device__ __forceinline__ unsigned long long sx64(unsigned long long v, int m) {
  unsigned lo = (unsigned)__shfl_xor((int)(unsigned)(v & 0xffffffffull), m, 64);
  unsigned hi = (unsigned)__shfl_xor((int)(unsigned)(v >> 32), m, 64);
  return ((unsigned long long)hi << 32) | lo;
}

__device__ __forceinline__ unsigned f2mono(float v) {
  unsigned b = __float_as_uint(v);
  return (b & 0x80000000u) ? ~b : (b | 0x80000000u);
}

// fp32 -> bf16 round-to-nearest-even
__device__ __forceinline__ short bfr(float f) {
  unsigned u = __float_as_uint(f);
  unsigned r = (u + 0x7fffu + ((u >> 16) & 1u)) >> 16;
  return (short)r;
}

__device__ __forceinline__ short8v cvt8(float4 a, float4 b) {
  short8v r;
  r[0] = bfr(a.x); r[1] = bfr(a.y); r[2] = bfr(a.z); r[3] = bfr(a.w);
  r[4] = bfr(b.x); r[5] = bfr(b.y); r[6] = bfr(b.z); r[7] = bfr(b.w);
  return r;
}

// split fp32 into bf16 hi (truncate) + bf16 lo (truncate of remainder)
__device__ __forceinline__ void split8(float4 a, float4 b, short8v& hi, short8v& lo) {
  const float f[8] = {a.x, a.y, a.z, a.w, b.x, b.y, b.z, b.w};
#pragma unroll
  for (int u = 0; u < 8; ++u) {
    const unsigned ui = __float_as_uint(f[u]);
    hi[u] = (short)(ui >> 16);
    const float hf = __uint_as_float(ui & 0xffff0000u);
    lo[u] = (short)(__float_as_uint(f[u] - hf) >> 16);
  }
}

// ------------------------------------------------- transpose (32x32 tiles)
__global__ __launch_bounds__(256) void transpose_k(const float* __restrict__ in,
    float* __restrict__ out, int R, int C) {
  __shared__ float ls[32][33];
  const int c0 = blockIdx.x * 32, r0 = blockIdx.y * 32;
  const int tx = threadIdx.x & 31, ty = threadIdx.x >> 5;
#pragma unroll
  for (int j = 0; j < 4; ++j) {
    int r = ty + j * 8;
    ls[r][tx] = in[(size_t)(r0 + r) * C + c0 + tx];
  }
  __syncthreads();
#pragma unroll
  for (int j = 0; j < 4; ++j) {
    int cc = ty + j * 8;
    out[(size_t)(c0 + cc) * R + r0 + tx] = ls[tx][cc];
  }
}

// ------------------------------------------------------------- im2col 3x3
__global__ __launch_bounds__(256) void im2col_k(const float* __restrict__ src,
    float* __restrict__ col) {
  int e = blockIdx.x * 256 + threadIdx.x;
  int pix = e / 2304;
  int kk = e - pix * 2304;
  int ci = kk / 9;
  int r = kk - ci * 9;
  int ky = r / 3, kx = r - ky * 3;
  int y = pix / 56, x = pix - y * 56;
  int yy = y + ky - 1, xx = x + kx - 1;
  float v = (yy >= 0 && yy < 56 && xx >= 0 && xx < 56)
                ? src[(size_t)ci * 3136 + yy * 56 + xx] : 0.f;
  col[(size_t)e] = v;
}

// ------------------------------------------ bf16 MFMA GEMM NT (fp32 I/O)
template <int RELU>
__global__ __launch_bounds__(256) void gemm_bt_bf16(const float* __restrict__ A,
    const float* __restrict__ B, const float* __restrict__ bias,
    float* __restrict__ C, int M, int N, int K) {
  __shared__ __align__(16) short As[64][40];
  __shared__ __align__(16) short Bs[64][40];
  const int n0 = blockIdx.x * 64;
  const int m0 = blockIdx.y * 64;
  const int t = threadIdx.x;
  const int w = t >> 6, l = t & 63;
  const int g = l >> 4, c = l & 15;
  const int wr = w >> 1, wc = w & 1;
  const int sr = t >> 2, seg = t & 3;
  const float* Ap = A + (size_t)(m0 + sr) * K + seg * 8;
  const float* Bp = B + (size_t)(n0 + sr) * K + seg * 8;
  f32x4 acc[2][2] = {};
  for (int k0 = 0; k0 < K; k0 += 32) {
    const float4 a1 = *(const float4*)(Ap + k0);
    const float4 a2 = *(const float4*)(Ap + k0 + 4);
    const float4 b1 = *(const float4*)(Bp + k0);
    const float4 b2 = *(const float4*)(Bp + k0 + 4);
    __syncthreads();
    *(short8v*)&As[sr][seg * 8] = cvt8(a1, a2);
    *(short8v*)&Bs[sr][seg * 8] = cvt8(b1, b2);
    __syncthreads();
    short8v af[2], bf[2];
#pragma unroll
    for (int mi = 0; mi < 2; ++mi)
      af[mi] = *(const short8v*)&As[wr * 32 + mi * 16 + c][g * 8];
#pragma unroll
    for (int ni = 0; ni < 2; ++ni)
      bf[ni] = *(const short8v*)&Bs[wc * 32 + ni * 16 + c][g * 8];
#pragma unroll
    for (int mi = 0; mi < 2; ++mi)
#pragma unroll
      for (int ni = 0; ni < 2; ++ni)
        acc[mi][ni] = __builtin_amdgcn_mfma_f32_16x16x32_bf16(
            af[mi], bf[ni], acc[mi][ni], 0, 0, 0);
  }
#pragma unroll
  for (int mi = 0; mi < 2; ++mi) {
#pragma unroll
    for (int ni = 0; ni < 2; ++ni) {
      const int col = n0 + wc * 32 + ni * 16 + c;
      const float bb = bias ? bias[col] : 0.f;
#pragma unroll
      for (int q = 0; q < 4; ++q) {
        const int m = m0 + wr * 32 + mi * 16 + g * 4 + q;
        float v = acc[mi][ni][q] + bb;
        if (RELU) v = fmaxf(v, 0.f);
        C[(size_t)m * N + col] = v;
      }
    }
  }
}

// --------------------------- fused Q/K/V projections, bf16 outputs
// grid (12, 49): sel = bx>>2 (0=Q,1=K,2=V), 4 n-tiles each. Q scaled by
// QSC; V written transposed AND chunk-swizzled for attn's slot-aligned PV.
__global__ __launch_bounds__(256) void proj_qkv_k(const float* __restrict__ QKIN,
    const float* __restrict__ X, const float* __restrict__ Wq,
    const float* __restrict__ Wk, const float* __restrict__ Wv,
    const float* __restrict__ bq, const float* __restrict__ bk,
    const float* __restrict__ bv, short* __restrict__ QB,
    short* __restrict__ KB, short* __restrict__ VT) {
  __shared__ __align__(16) short As[64][40];
  __shared__ __align__(16) short Bs[64][40];
  const int sel = blockIdx.x >> 2;
  const int n0 = (blockIdx.x & 3) * 64;
  const int m0 = blockIdx.y * 64;
  const float* A = (sel < 2) ? QKIN : X;
  const float* B = (sel == 0) ? Wq : (sel == 1) ? Wk : Wv;
  const float* bias = (sel == 0) ? bq : (sel == 1) ? bk : bv;
  const int t = threadIdx.x;
  const int w = t >> 6, l = t & 63;
  const int g = l >> 4, c = l & 15;
  const int wr = w >> 1, wc = w & 1;
  const int sr = t >> 2, seg = t & 3;
  const float* Ap = A + (size_t)(m0 + sr) * CD + seg * 8;
  const float* Bp = B + (size_t)(n0 + sr) * CD + seg * 8;
  f32x4 acc[2][2] = {};
  for (int k0 = 0; k0 < CD; k0 += 32) {
    const float4 a1 = *(const float4*)(Ap + k0);
    const float4 a2 = *(const float4*)(Ap + k0 + 4);
    const float4 b1 = *(const float4*)(Bp + k0);
    const float4 b2 = *(const float4*)(Bp + k0 + 4);
    __syncthreads();
    *(short8v*)&As[sr][seg * 8] = cvt8(a1, a2);
    *(short8v*)&Bs[sr][seg * 8] = cvt8(b1, b2);
    __syncthreads();
    short8v af[2], bf[2];
#pragma unroll
    for (int mi = 0; mi < 2; ++mi)
      af[mi] = *(const short8v*)&As[wr * 32 + mi * 16 + c][g * 8];
#pragma unroll
    for (int ni = 0; ni < 2; ++ni)
      bf[ni] = *(const short8v*)&Bs[wc * 32 + ni * 16 + c][g * 8];
#pragma unroll
    for (int mi = 0; mi < 2; ++mi)
#pragma unroll
      for (int ni = 0; ni < 2; ++ni)
        acc[mi][ni] = __builtin_amdgcn_mfma_f32_16x16x32_bf16(
            af[mi], bf[ni], acc[mi][ni], 0, 0, 0);
  }
#pragma unroll
  for (int mi = 0; mi < 2; ++mi) {
#pragma unroll
    for (int ni = 0; ni < 2; ++ni) {
      const int col = n0 + wc * 32 + ni * 16 + c;
      const float bb = bias[col];
      if (sel == 2) {
        // V^T swizzled: token mb..mb+3 -> chunkbase + p(mb) + 0..3
        const int mb = m0 + wr * 32 + mi * 16 + g * 4;
        const int pidx = (mb & ~31) + ((mb >> 4) & 1) * 4 + ((mb >> 2) & 3) * 8;
        uint2 pk;
        const float v0 = acc[mi][ni][0] + bb, v1 = acc[mi][ni][1] + bb;
        const float v2 = acc[mi][ni][2] + bb, v3 = acc[mi][ni][3] + bb;
        pk.x = (unsigned)(unsigned short)bfr(v0) | ((unsigned)(unsigned short)bfr(v1) << 16);
        pk.y = (unsigned)(unsigned short)bfr(v2) | ((unsigned)(unsigned short)bfr(v3) << 16);
        *(uint2*)&VT[(size_t)col * N_TOK + pidx] = pk;
      } else {
        short* Ct = (sel == 0) ? QB : KB;
        const float qs = (sel == 0) ? QSC : 1.f;
#pragma unroll
        for (int q = 0; q < 4; ++q) {
          const int m = m0 + wr * 32 + mi * 16 + g * 4 + q;
          Ct[(size_t)m * CD + col] = bfr((acc[mi][ni][q] + bb) * qs);
        }
      }
    }
  }
}

// ------------------------- Gram G = X X^T via split-bf16 (hi+lo) MFMA
__global__ __launch_bounds__(256) void gemm_syr2_k(const float* __restrict__ A,
    float* __restrict__ C) {
  __shared__ __align__(16) short AsH[64][40];
  __shared__ __align__(16) short AsL[64][40];
  __shared__ __align__(16) short BsH[64][40];
  __shared__ __align__(16) short BsL[64][40];
  int bid = blockIdx.x;
  int bi = (int)((sqrtf(8.f * (float)bid + 1.f) - 1.f) * 0.5f);
  while ((bi + 1) * (bi + 2) / 2 <= bid) ++bi;
  while (bi * (bi + 1) / 2 > bid) --bi;
  const int bj = bid - bi * (bi + 1) / 2;
  const int m0 = bi * 64, n0 = bj * 64;
  const int t = threadIdx.x;
  const int w = t >> 6, l = t & 63;
  const int g = l >> 4, c = l & 15;
  const int wr = w >> 1, wc = w & 1;
  const int sr = t >> 2, seg = t & 3;
  const float* Ap = A + (size_t)(m0 + sr) * CD + seg * 8;
  const float* Bp = A + (size_t)(n0 + sr) * CD + seg * 8;
  f32x4 acc[2][2] = {};
  for (int k0 = 0; k0 < CD; k0 += 32) {
    const float4 a1 = *(const float4*)(Ap + k0);
    const float4 a2 = *(const float4*)(Ap + k0 + 4);
    const float4 b1 = *(const float4*)(Bp + k0);
    const float4 b2 = *(const float4*)(Bp + k0 + 4);
    __syncthreads();
    short8v h8, l8;
    split8(a1, a2, h8, l8);
    *(short8v*)&AsH[sr][seg * 8] = h8;
    *(short8v*)&AsL[sr][seg * 8] = l8;
    split8(b1, b2, h8, l8);
    *(short8v*)&BsH[sr][seg * 8] = h8;
    *(short8v*)&BsL[sr][seg * 8] = l8;
    __syncthreads();
    short8v afH[2], afL[2], bfH[2], bfL[2];
#pragma unroll
    for (int mi = 0; mi < 2; ++mi) {
      afH[mi] = *(const short8v*)&AsH[wr * 32 + mi * 16 + c][g * 8];
      afL[mi] = *(const short8v*)&AsL[wr * 32 + mi * 16 + c][g * 8];
    }
#pragma unroll
    for (int ni = 0; ni < 2; ++ni) {
      bfH[ni] = *(const short8v*)&BsH[wc * 32 + ni * 16 + c][g * 8];
      bfL[ni] = *(const short8v*)&BsL[wc * 32 + ni * 16 + c][g * 8];
    }
#pragma unroll
    for (int mi = 0; mi < 2; ++mi)
#pragma unroll
      for (int ni = 0; ni < 2; ++ni) {
        acc[mi][ni] = __builtin_amdgcn_mfma_f32_16x16x32_bf16(afH[mi], bfH[ni], acc[mi][ni], 0, 0, 0);
        acc[mi][ni] = __builtin_amdgcn_mfma_f32_16x16x32_bf16(afH[mi], bfL[ni], acc[mi][ni], 0, 0, 0);
        acc[mi][ni] = __builtin_amdgcn_mfma_f32_16x16x32_bf16(afL[mi], bfH[ni], acc[mi][ni], 0, 0, 0);
      }
  }
#pragma unroll
  for (int mi = 0; mi < 2; ++mi)
#pragma unroll
    for (int ni = 0; ni < 2; ++ni) {
      const int col = n0 + wc * 32 + ni * 16 + c;
#pragma unroll
      for (int q = 0; q < 4; ++q) {
        const int m = m0 + wr * 32 + mi * 16 + g * 4 + q;
        const float v = acc[mi][ni][q];
        C[(size_t)m * N_TOK + col] = v;
        C[(size_t)col * N_TOK + m] = v;
      }
    }
}

// ------------------------------------------------------------ conv2 (8ch)
__global__ __launch_bounds__(256) void conv2_k(const float* __restrict__ t1,
    const float* __restrict__ w, const float* __restrict__ b,
    float* __restrict__ gp) {
  __shared__ float ws3[9 * 8 * 132];
  const int t = threadIdx.x;
  for (int e = t; e < 9216; e += 256) {
    int r = e >> 10;
    int rem = e & 1023;
    int co = rem >> 7;
    int ci = rem & 127;
    ws3[(r * 8 + co) * 132 + ci] = w[((size_t)co * 128 + ci) * 9 + r];
  }
  __syncthreads();
  const int pix = blockIdx.x * 32 + (t >> 3);
  const int co = t & 7;
  const int y = pix / 56, x = pix - y * 56;
  float acc = b[co];
  for (int ky = 0; ky < 3; ++ky) {
    int yy = y + ky - 1;
    if (yy < 0 || yy >= 56) continue;
    for (int kx = 0; kx < 3; ++kx) {
      int xx = x + kx - 1;
      if (xx < 0 || xx >= 56) continue;
      const float4* tp = (const float4*)&t1[(size_t)(yy * 56 + xx) * 128];
      const float* wp = &ws3[((ky * 3 + kx) * 8 + co) * 132];
#pragma unroll
      for (int c4 = 0; c4 < 32; ++c4) {
        const float4 tv = tp[c4];
        const float4 wv = *(const float4*)&wp[c4 * 4];
        acc += tv.x * wv.x + tv.y * wv.y + tv.z * wv.z + tv.w * wv.w;
      }
    }
  }
  gp[pix * 8 + co] = 1.f / (1.f + expf(-acc));
}

// ------------------------------------------------------------- row ||x||^2
__global__ __launch_bounds__(64) void rowsq_k(const float* __restrict__ x,
                                              float* __restrict__ sq) {
  const int i = blockIdx.x, lane = threadIdx.x;
  const float4 v = ((const float4*)&x[(size_t)i * CD])[lane];
  float s = v.x * v.x + v.y * v.y + v.z * v.z + v.w * v.w;
#pragma unroll
  for (int m = 1; m < 64; m <<= 1) s += __shfl_xor(s, m, 64);
  if (lane == 0) sq[i] = s;
}

// -------------------------------------------------- top-16 NN + in-degree
__global__ __launch_bounds__(256) void topk_k(const float* __restrict__ G,
    const float* __restrict__ sq, int* __restrict__ near) {
  __shared__ unsigned long long wmin[4];
  const int i = blockIdx.x;
  const int t = threadIdx.x;
  const float sqi = sq[i];
  unsigned long long key[13];
#pragma unroll
  for (int e = 0; e < 13; ++e) {
    int j = t + (e << 8);
    float d2 = INFINITY;
    if (j < N_TOK) d2 = (sqi - 2.f * G[(size_t)i * N_TOK + j]) + sq[j];
    key[e] = ((unsigned long long)f2mono(d2) << 32) | (unsigned)j;
  }
  unsigned long long last = 0ull;
#pragma unroll 1
  for (int r = 0; r < 16; ++r) {
    unsigned long long best = ~0ull;
#pragma unroll
    for (int e = 0; e < 13; ++e) {
      bool ok = (key[e] > last) && (key[e] < best);
      best = ok ? key[e] : best;
    }
#pragma unroll
    for (int m = 1; m < 64; m <<= 1) {
      unsigned long long o = sx64(best, m);
      best = (o < best) ? o : best;
    }
    __syncthreads();
    if ((t & 63) == 0) wmin[t >> 6] = best;
    __syncthreads();
    unsigned long long b0 = wmin[0] < wmin[1] ? wmin[0] : wmin[1];
    unsigned long long b1 = wmin[2] < wmin[3] ? wmin[2] : wmin[3];
    best = b0 < b1 ? b0 : b1;
    if (t == 0) atomicAdd(&near[(unsigned)(best & 0xffffffffu)], 1);
    last = best;
  }
}

// ------------------------------------------------------------- max(near)
__global__ __launch_bounds__(256) void nearmax_k(const int* __restrict__ near,
                                                 int* __restrict__ nmax) {
  __shared__ int sm[4];
  const int t = threadIdx.x;
  int m = 0;
  for (int j = t; j < N_TOK; j += 256) m = max(m, near[j]);
#pragma unroll
  for (int s = 1; s < 64; s <<= 1) m = max(m, __shfl_xor(m, s, 64));
  if ((t & 63) == 0) sm[t >> 6] = m;
  __syncthreads();
  if (t == 0) nmax[0] = max(max(sm[0], sm[1]), max(sm[2], sm[3]));
}

// ------------------------------------------------ qk_in = x + emb[ni(near)]
__global__ __launch_bounds__(256) void qkin_k(const float* __restrict__ x,
    const int* __restrict__ near, const int* __restrict__ nmax,
    const float* __restrict__ emb, float* __restrict__ qkin) {
  const int i = blockIdx.x, t = threadIdx.x;
  const float nf = (float)near[i], mf = (float)nmax[0];
  const int ni = (int)(nf / mf * 9.0f);
  qkin[(size_t)i * CD + t] = x[(size_t)i * CD + t] + emb[ni * CD + t];
}

// ---------------------------------- gp [tok][8] -> gpT [8][tok], * log2e
__global__ __launch_bounds__(256) void gpt_k(const float* __restrict__ gp,
                                             float* __restrict__ gpT) {
  const int e = blockIdx.x * 256 + threadIdx.x;
  const int i = e >> 3, h = e & 7;
  gpT[h * N_TOK + i] = gp[e] * LOG2E;
}

// ------------- flash attention v4: slot-aligned PV, defer-max, no LDS
// grid (49, 8, 4): 4 waves/block, 16 queries/wave; z = j-split quarter.
// Swapped QK^T: lane (g,c) holds 16 j-slot scores for query c. PV consumes
// the lane's own P registers (k-enum = slot order); V^T is chunk-swizzled.
__global__ __launch_bounds__(256) void attn_v4_k(const short* __restrict__ Qb,
    const short* __restrict__ Kb, const short* __restrict__ Vt,
    const float* __restrict__ gpT, float* __restrict__ OP,
    float* __restrict__ ML) {
  const int h = blockIdx.y, sp = blockIdx.z;
  const int t = threadIdx.x;
  const int w = t >> 6, l = t & 63;
  const int g = l >> 4, c = l & 15;
  const int iw = (blockIdx.x * 4 + w) * 16;
  const size_t hoff = (size_t)h * DH;
  const short8v qf = *(const short8v*)&Qb[(size_t)(iw + c) * CD + hoff + g * 8];
  const float gpi = gpT[h * N_TOK + iw + c];
  const int jt0 = sp * 12 + (sp ? 1 : 0);
  const int jt1 = jt0 + (sp ? 12 : 13);
  float mrun = -INFINITY, lpart = 0.f;
  f32x4 oaccT[2] = {};
  const f32x4 zz = {0.f, 0.f, 0.f, 0.f};

  short8v kf[4];
#pragma unroll
  for (int sub = 0; sub < 4; ++sub)
    kf[sub] = *(const short8v*)&Kb[(size_t)(jt0 * 64 + sub * 16 + c) * CD + hoff + g * 8];

  for (int jt = jt0; jt < jt1; ++jt) {
    const int j0 = jt * 64;
    // QK^T swapped: sacc[sub][q] = S[slot = sub*16+g*4+q][query c] (log2 dom.)
    f32x4 sacc[4];
#pragma unroll
    for (int sub = 0; sub < 4; ++sub)
      sacc[sub] = __builtin_amdgcn_mfma_f32_16x16x32_bf16(kf[sub], qf, zz, 0, 0, 0);
    // V^T fragments (swizzled storage -> one 16B load each), issued early
    short8v vf[2][2];
#pragma unroll
    for (int ch = 0; ch < 2; ++ch)
#pragma unroll
      for (int ds = 0; ds < 2; ++ds)
        vf[ch][ds] = *(const short8v*)&Vt[(hoff + ds * 16 + c) * (size_t)N_TOK + j0 + ch * 32 + g * 8];
    // prefetch next K tile
    if (jt + 1 < jt1) {
#pragma unroll
      for (int sub = 0; sub < 4; ++sub)
        kf[sub] = *(const short8v*)&Kb[(size_t)(j0 + 64 + sub * 16 + c) * CD + hoff + g * 8];
    }
    float4 gj[4];
#pragma unroll
    for (int sub = 0; sub < 4; ++sub)
      gj[sub] = *(const float4*)&gpT[h * N_TOK + j0 + sub * 16 + g * 4];
    // bias (log2 domain)
    float sv[16];
#pragma unroll
    for (int sub = 0; sub < 4; ++sub) {
      sv[sub * 4 + 0] = sacc[sub][0] + fabsf(gpi - gj[sub].x);
      sv[sub * 4 + 1] = sacc[sub][1] + fabsf(gpi - gj[sub].y);
      sv[sub * 4 + 2] = sacc[sub][2] + fabsf(gpi - gj[sub].z);
      sv[sub * 4 + 3] = sacc[sub][3] + fabsf(gpi - gj[sub].w);
    }
    // lane-local tree max over 16 slots
    float a0 = fmaxf(sv[0], sv[1]),  a1 = fmaxf(sv[2], sv[3]);
    float a2 = fmaxf(sv[4], sv[5]),  a3 = fmaxf(sv[6], sv[7]);
    float a4 = fmaxf(sv[8], sv[9]),  a5 = fmaxf(sv[10], sv[11]);
    float a6 = fmaxf(sv[12], sv[13]), a7 = fmaxf(sv[14], sv[15]);
    float b0 = fmaxf(a0, a1), b1 = fmaxf(a2, a3);
    float b2 = fmaxf(a4, a5), b3 = fmaxf(a6, a7);
    const float mx = fmaxf(fmaxf(b0, b1), fmaxf(b2, b3));
    // defer-max: rebase only if some lane's tile max exceeds mrun + 11
    if (!__all(mx - mrun <= 11.f)) {
      float mn = mx;
      mn = fmaxf(mn, __shfl_xor(mn, 16, 64));
      mn = fmaxf(mn, __shfl_xor(mn, 32, 64));
      mn = fmaxf(mn, mrun);
      const float sc = __builtin_amdgcn_exp2f(mrun - mn);
      oaccT[0][0] *= sc; oaccT[0][1] *= sc; oaccT[0][2] *= sc; oaccT[0][3] *= sc;
      oaccT[1][0] *= sc; oaccT[1][1] *= sc; oaccT[1][2] *= sc; oaccT[1][3] *= sc;
      lpart *= sc;
      mrun = mn;
    }
    // exp2 + truncate to bf16 (consistent for l-sum and PV)
    unsigned pu[16];
    float pvt[16];
#pragma unroll
    for (int e = 0; e < 16; ++e) {
      const float p = __builtin_amdgcn_exp2f(sv[e] - mrun);
      pu[e] = __float_as_uint(p) & 0xffff0000u;
      pvt[e] = __uint_as_float(pu[e]);
    }
    float s0 = (pvt[0] + pvt[1]) + (pvt[2] + pvt[3]);
    float s1 = (pvt[4] + pvt[5]) + (pvt[6] + pvt[7]);
    float s2 = (pvt[8] + pvt[9]) + (pvt[10] + pvt[11]);
    float s3 = (pvt[12] + pvt[13]) + (pvt[14] + pvt[15]);
    lpart += (s0 + s1) + (s2 + s3);
    // pack P pairs: one v_perm per dword
    unsigned pk8[8];
#pragma unroll
    for (int sub = 0; sub < 4; ++sub) {
      pk8[2 * sub + 0] = __builtin_amdgcn_perm(pu[4 * sub + 1], pu[4 * sub + 0], 0x07060302u);
      pk8[2 * sub + 1] = __builtin_amdgcn_perm(pu[4 * sub + 3], pu[4 * sub + 2], 0x07060302u);
    }
    union { unsigned u[4]; short8v s; } pf0, pf1;
    pf0.u[0] = pk8[0]; pf0.u[1] = pk8[1]; pf0.u[2] = pk8[2]; pf0.u[3] = pk8[3];
    pf1.u[0] = pk8[4]; pf1.u[1] = pk8[5]; pf1.u[2] = pk8[6]; pf1.u[3] = pk8[7];
    // PV: O^T[d][query c]; k-enum = slot order, P frag = own registers
    oaccT[0] = __builtin_amdgcn_mfma_f32_16x16x32_bf16(vf[0][0], pf0.s, oaccT[0], 0, 0, 0);
    oaccT[1] = __builtin_amdgcn_mfma_f32_16x16x32_bf16(vf[0][1], pf0.s, oaccT[1], 0, 0, 0);
    oaccT[0] = __builtin_amdgcn_mfma_f32_16x16x32_bf16(vf[1][0], pf1.s, oaccT[0], 0, 0, 0);
    oaccT[1] = __builtin_amdgcn_mfma_f32_16x16x32_bf16(vf[1][1], pf1.s, oaccT[1], 0, 0, 0);
  }
  // store partial O^T (unnormalized): lane (g,c) has d = ds*16+g*4+q, query c
  const size_t ob = (size_t)(sp * 8 + h) * N_TOK + iw;
  *(f32x4*)&OP[(ob + c) * 32 + g * 4] = oaccT[0];
  *(f32x4*)&OP[(ob + c) * 32 + 16 + g * 4] = oaccT[1];
  float ls = lpart;
  ls += __shfl_xor(ls, 16, 64);
  ls += __shfl_xor(ls, 32, 64);
  if (g == 0) {
    ML[(ob + c) * 2 + 0] = mrun;
    ML[(ob + c) * 2 + 1] = ls;
  }
}

// ---------------------------------------- combine the four j-split quarters
__global__ __launch_bounds__(256) void attn_comb_k(const float* __restrict__ OP,
    const float* __restrict__ ML, float* __restrict__ O1) {
  const int i = blockIdx.x, t = threadIdx.x;
  const int h = t >> 5, d = t & 31;
  float m[4], lv[4];
  float M = -INFINITY;
#pragma unroll
  for (int s = 0; s < 4; ++s) {
    const size_t b = (size_t)(s * 8 + h) * N_TOK + i;
    m[s] = ML[b * 2]; lv[s] = ML[b * 2 + 1];
    M = fmaxf(M, m[s]);
  }
  float num = 0.f, den = 0.f;
#pragma unroll
  for (int s = 0; s < 4; ++s) {
    const size_t b = (size_t)(s * 8 + h) * N_TOK + i;
    const float wgt = __builtin_amdgcn_exp2f(m[s] - M);
    num += wgt * OP[b * 32 + d];
    den += wgt * lv[s];
  }
  O1[(size_t)i * CD + t] = num / den;
}

// ---------------------- LayerNorm (+residual) (+optional row-sq output)
__global__ __launch_bounds__(256) void ln_k(const float* __restrict__ xin,
    const float* __restrict__ add, const float* __restrict__ g,
    const float* __restrict__ b, float* __restrict__ xout,
    float* __restrict__ sqout) {
  __shared__ float red1[4];
  __shared__ float red2[4];
  const int i = blockIdx.x, t = threadIdx.x;
  float v = xin[(size_t)i * CD + t];
  if (add) v += add[(size_t)i * CD + t];
  float s = v;
#pragma unroll
  for (int m = 1; m < 64; m <<= 1) s += __shfl_xor(s, m, 64);
  if ((t & 63) == 0) red1[t >> 6] = s;
  __syncthreads();
  const float mean = (red1[0] + red1[1] + red1[2] + red1[3]) * (1.f / 256.f);
  const float d = v - mean;
  float s2 = d * d;
#pragma unroll
  for (int m = 1; m < 64; m <<= 1) s2 += __shfl_xor(s2, m, 64);
  if ((t & 63) == 0) red2[t >> 6] = s2;
  __syncthreads();
  const float var = (red2[0] + red2[1] + red2[2] + red2[3]) * (1.f / 256.f);
  const float xo = d * rsqrtf(var + 1e-5f) * g[t] + b[t];
  xout[(size_t)i * CD + t] = xo;
  if (sqout) {
    float s3 = xo * xo;
#pragma unroll
    for (int m = 1; m < 64; m <<= 1) s3 += __shfl_xor(s3, m, 64);
    __syncthreads();
    if ((t & 63) == 0) red1[t >> 6] = s3;
    __syncthreads();
    if (t == 0) sqout[i] = red1[0] + red1[1] + red1[2] + red1[3];
  }
}

// ---------------------------------------------------------------- launch
extern "C" void kernel_launch(void* const* d_in, const int* in_sizes, int n_in,
                              void* d_out, int out_size, void* d_ws, size_t ws_size,
                              hipStream_t stream) {
  const float* src  = (const float*)d_in[0];
  const float* c1w  = (const float*)d_in[1];
  const float* c1b  = (const float*)d_in[2];
  const float* c2w  = (const float*)d_in[3];
  const float* c2b  = (const float*)d_in[4];
  const float* nemb = (const float*)d_in[5];
  const float* Wq   = (const float*)d_in[6];
  const float* bq   = (const float*)d_in[7];
  const float* Wk   = (const float*)d_in[8];
  const float* bk   = (const float*)d_in[9];
  const float* Wv   = (const float*)d_in[10];
  const float* bv   = (const float*)d_in[11];
  const float* Wo   = (const float*)d_in[12];
  const float* bo   = (const float*)d_in[13];
  const float* W1   = (const float*)d_in[14];
  const float* b1   = (const float*)d_in[15];
  const float* W2   = (const float*)d_in[16];
  const float* b2   = (const float*)d_in[17];
  const float* ln1g = (const float*)d_in[18];
  const float* ln1b = (const float*)d_in[19];
  const float* ln2g = (const float*)d_in[20];
  const float* ln2b = (const float*)d_in[21];
  const float* ng   = (const float*)d_in[22];
  const float* nb   = (const float*)d_in[23];

  float* ws = (float*)d_ws;
  const size_t NC = (size_t)N_TOK * CD;          // 802816
  float* X    = ws;
  float* QKIN = X + NC;
  float* O1   = QKIN + NC;
  float* TMP  = O1 + NC;
  float* FF1  = TMP + NC;                        // 3136*1024
  float* OP   = FF1;                             // 4*8*3136*32 == |FF1|
  float* ML   = OP + (size_t)4 * 8 * N_TOK * 32; // lands in G (free then)
  float* G    = FF1 + (size_t)N_TOK * DFFD;      // 3136*3136 (also im2col)
  float* T1   = G + (size_t)N_TOK * N_TOK;       // 3136*128
  float* GP   = T1 + (size_t)N_TOK * 128;        // 3136*8
  float* GPT  = GP + (size_t)N_TOK * NHD;        // 3136*8
  float* SQF  = GPT + (size_t)N_TOK * NHD;       // 3136
  short* QB16 = (short*)(SQF + N_TOK);
  short* KB16 = QB16 + NC;
  short* VT16 = KB16 + NC;
  int*   NEAR = (int*)(VT16 + NC);
  int*   NMAX = NEAR + N_TOK;

  // conv positional encoder
  im2col_k<<<28224, 256, 0, stream>>>(src, G);
  gemm_bt_bf16<1><<<dim3(2, 49), 256, 0, stream>>>(G, c1w, c1b, T1, N_TOK, 128, 2304);
  conv2_k<<<98, 256, 0, stream>>>(T1, c2w, c2b, GP);
  gpt_k<<<98, 256, 0, stream>>>(GP, GPT);
  transpose_k<<<dim3(98, 8), 256, 0, stream>>>(src, X, 256, N_TOK);
  rowsq_k<<<N_TOK, 64, 0, stream>>>(X, SQF);

  for (int l = 0; l < 4; ++l) {
    // ---- kNN graph -> near counts (split-bf16 MFMA Gram)
    gemm_syr2_k<<<1225, 256, 0, stream>>>(X, G);
    (void)hipMemsetAsync(NEAR, 0, N_TOK * sizeof(int), stream);
    topk_k<<<N_TOK, 256, 0, stream>>>(G, SQF, NEAR);
    nearmax_k<<<1, 256, 0, stream>>>(NEAR, NMAX);
    qkin_k<<<N_TOK, 256, 0, stream>>>(X, NEAR, NMAX, nemb, QKIN);
    // ---- fused Q/K/V projections (Q pre-scaled log2 domain, V^T swizzled)
    proj_qkv_k<<<dim3(12, 49), 256, 0, stream>>>(QKIN, X,
        Wq + (size_t)l * 65536, Wk + (size_t)l * 65536, Wv + (size_t)l * 65536,
        bq + l * 256, bk + l * 256, bv + l * 256, QB16, KB16, VT16);
    // ---- attention (no-LDS, defer-max, j-split 4) + combine
    attn_v4_k<<<dim3(49, 8, 4), 256, 0, stream>>>(QB16, KB16, VT16, GPT, OP, ML);
    attn_comb_k<<<N_TOK, 256, 0, stream>>>(OP, ML, O1);
    gemm_bt_bf16<0><<<dim3(4, 49), 256, 0, stream>>>(O1, Wo + (size_t)l * 65536, bo + l * 256, TMP, N_TOK, CD, CD);
    ln_k<<<N_TOK, 256, 0, stream>>>(X, TMP, ln1g + l * 256, ln1b + l * 256, X, nullptr);
    // ---- FFN
    gemm_bt_bf16<1><<<dim3(16, 49), 256, 0, stream>>>(X, W1 + (size_t)l * 262144, b1 + l * 1024, FF1, N_TOK, DFFD, CD);
    gemm_bt_bf16<0><<<dim3(4, 49), 256, 0, stream>>>(FF1, W2 + (size_t)l * 262144, b2 + l * 256, TMP, N_TOK, CD, DFFD);
    ln_k<<<N_TOK, 256, 0, stream>>>(X, TMP, ln2g + l * 256, ln2b + l * 256, X, SQF);
  }
  // final LN + transpose to [1,C,H,W]
  ln_k<<<N_TOK, 256, 0, stream>>>(X, nullptr, ng, nb, TMP, nullptr);
  transpose_k<<<dim3(8, 98), 256, 0, stream>>>(TMP, (float*)d_out, N_TOK, 256);
}

// Round 7
// 955.134 us; speedup vs baseline: 2.7074x; 1.1602x over previous
//
#include <hip/hip_runtime.h>
#include <math.h>

#define N_TOK 3136
#define CD    256
#define NHD   8
#define DH    32
#define DFFD  1024
#define SCALE 0.17677669529663687f  /* 32^-0.5 */
#define LOG2E 1.4426950408889634f
#define QSC   (SCALE * LOG2E)

typedef __attribute__((ext_vector_type(8))) short short8v;
typedef __attribute__((ext_vector_type(4))) float f32x4;

// ---------------------------------------------------------------- utils
__device__ __forceinline__ unsigned long long sx64(unsigned long long v, int m) {
  unsigned lo = (unsigned)__shfl_xor((int)(unsigned)(v & 0xffffffffull), m, 64);
  unsigned hi = (unsigned)__shfl_xor((int)(unsigned)(v >> 32), m, 64);
  return ((unsigned long long)hi << 32) | lo;
}

__device__ __forceinline__ unsigned f2mono(float v) {
  unsigned b = __float_as_uint(v);
  return (b & 0x80000000u) ? ~b : (b | 0x80000000u);
}

// fp32 -> bf16 round-to-nearest-even
__device__ __forceinline__ short bfr(float f) {
  unsigned u = __float_as_uint(f);
  unsigned r = (u + 0x7fffu + ((u >> 16) & 1u)) >> 16;
  return (short)r;
}

__device__ __forceinline__ short8v cvt8(float4 a, float4 b) {
  short8v r;
  r[0] = bfr(a.x); r[1] = bfr(a.y); r[2] = bfr(a.z); r[3] = bfr(a.w);
  r[4] = bfr(b.x); r[5] = bfr(b.y); r[6] = bfr(b.z); r[7] = bfr(b.w);
  return r;
}

// split fp32 into bf16 hi (truncate) + bf16 lo (truncate of remainder)
__device__ __forceinline__ void split8(float4 a, float4 b, short8v& hi, short8v& lo) {
  const float f[8] = {a.x, a.y, a.z, a.w, b.x, b.y, b.z, b.w};
#pragma unroll
  for (int u = 0; u < 8; ++u) {
    const unsigned ui = __float_as_uint(f[u]);
    hi[u] = (short)(ui >> 16);
    const float hf = __uint_as_float(ui & 0xffff0000u);
    lo[u] = (short)(__float_as_uint(f[u] - hf) >> 16);
  }
}

// ------------------------------------------------- transpose (32x32 tiles)
__global__ __launch_bounds__(256) void transpose_k(const float* __restrict__ in,
    float* __restrict__ out, int R, int C) {
  __shared__ float ls[32][33];
  const int c0 = blockIdx.x * 32, r0 = blockIdx.y * 32;
  const int tx = threadIdx.x & 31, ty = threadIdx.x >> 5;
#pragma unroll
  for (int j = 0; j < 4; ++j) {
    int r = ty + j * 8;
    ls[r][tx] = in[(size_t)(r0 + r) * C + c0 + tx];
  }
  __syncthreads();
#pragma unroll
  for (int j = 0; j < 4; ++j) {
    int cc = ty + j * 8;
    out[(size_t)(c0 + cc) * R + r0 + tx] = ls[tx][cc];
  }
}

// ------------------------------------------------------------- im2col 3x3
__global__ __launch_bounds__(256) void im2col_k(const float* __restrict__ src,
    float* __restrict__ col) {
  int e = blockIdx.x * 256 + threadIdx.x;
  int pix = e / 2304;
  int kk = e - pix * 2304;
  int ci = kk / 9;
  int r = kk - ci * 9;
  int ky = r / 3, kx = r - ky * 3;
  int y = pix / 56, x = pix - y * 56;
  int yy = y + ky - 1, xx = x + kx - 1;
  float v = (yy >= 0 && yy < 56 && xx >= 0 && xx < 56)
                ? src[(size_t)ci * 3136 + yy * 56 + xx] : 0.f;
  col[(size_t)e] = v;
}

// ------------------------------------------ bf16 MFMA GEMM NT (fp32 I/O)
template <int RELU>
__global__ __launch_bounds__(256) void gemm_bt_bf16(const float* __restrict__ A,
    const float* __restrict__ B, const float* __restrict__ bias,
    float* __restrict__ C, int M, int N, int K) {
  __shared__ __align__(16) short As[64][40];
  __shared__ __align__(16) short Bs[64][40];
  const int n0 = blockIdx.x * 64;
  const int m0 = blockIdx.y * 64;
  const int t = threadIdx.x;
  const int w = t >> 6, l = t & 63;
  const int g = l >> 4, c = l & 15;
  const int wr = w >> 1, wc = w & 1;
  const int sr = t >> 2, seg = t & 3;
  const float* Ap = A + (size_t)(m0 + sr) * K + seg * 8;
  const float* Bp = B + (size_t)(n0 + sr) * K + seg * 8;
  f32x4 acc[2][2] = {};
  for (int k0 = 0; k0 < K; k0 += 32) {
    const float4 a1 = *(const float4*)(Ap + k0);
    const float4 a2 = *(const float4*)(Ap + k0 + 4);
    const float4 b1 = *(const float4*)(Bp + k0);
    const float4 b2 = *(const float4*)(Bp + k0 + 4);
    __syncthreads();
    *(short8v*)&As[sr][seg * 8] = cvt8(a1, a2);
    *(short8v*)&Bs[sr][seg * 8] = cvt8(b1, b2);
    __syncthreads();
    short8v af[2], bf[2];
#pragma unroll
    for (int mi = 0; mi < 2; ++mi)
      af[mi] = *(const short8v*)&As[wr * 32 + mi * 16 + c][g * 8];
#pragma unroll
    for (int ni = 0; ni < 2; ++ni)
      bf[ni] = *(const short8v*)&Bs[wc * 32 + ni * 16 + c][g * 8];
#pragma unroll
    for (int mi = 0; mi < 2; ++mi)
#pragma unroll
      for (int ni = 0; ni < 2; ++ni)
        acc[mi][ni] = __builtin_amdgcn_mfma_f32_16x16x32_bf16(
            af[mi], bf[ni], acc[mi][ni], 0, 0, 0);
  }
#pragma unroll
  for (int mi = 0; mi < 2; ++mi) {
#pragma unroll
    for (int ni = 0; ni < 2; ++ni) {
      const int col = n0 + wc * 32 + ni * 16 + c;
      const float bb = bias ? bias[col] : 0.f;
#pragma unroll
      for (int q = 0; q < 4; ++q) {
        const int m = m0 + wr * 32 + mi * 16 + g * 4 + q;
        float v = acc[mi][ni][q] + bb;
        if (RELU) v = fmaxf(v, 0.f);
        C[(size_t)m * N + col] = v;
      }
    }
  }
}

// --------------------------- fused Q/K/V projections, bf16 outputs
// grid (12, 49): sel = bx>>2 (0=Q,1=K,2=V), 4 n-tiles each. Q scaled by
// QSC; V written transposed AND chunk-swizzled for attn's slot-aligned PV.
__global__ __launch_bounds__(256) void proj_qkv_k(const float* __restrict__ QKIN,
    const float* __restrict__ X, const float* __restrict__ Wq,
    const float* __restrict__ Wk, const float* __restrict__ Wv,
    const float* __restrict__ bq, const float* __restrict__ bk,
    const float* __restrict__ bv, short* __restrict__ QB,
    short* __restrict__ KB, short* __restrict__ VT) {
  __shared__ __align__(16) short As[64][40];
  __shared__ __align__(16) short Bs[64][40];
  const int sel = blockIdx.x >> 2;
  const int n0 = (blockIdx.x & 3) * 64;
  const int m0 = blockIdx.y * 64;
  const float* A = (sel < 2) ? QKIN : X;
  const float* B = (sel == 0) ? Wq : (sel == 1) ? Wk : Wv;
  const float* bias = (sel == 0) ? bq : (sel == 1) ? bk : bv;
  const int t = threadIdx.x;
  const int w = t >> 6, l = t & 63;
  const int g = l >> 4, c = l & 15;
  const int wr = w >> 1, wc = w & 1;
  const int sr = t >> 2, seg = t & 3;
  const float* Ap = A + (size_t)(m0 + sr) * CD + seg * 8;
  const float* Bp = B + (size_t)(n0 + sr) * CD + seg * 8;
  f32x4 acc[2][2] = {};
  for (int k0 = 0; k0 < CD; k0 += 32) {
    const float4 a1 = *(const float4*)(Ap + k0);
    const float4 a2 = *(const float4*)(Ap + k0 + 4);
    const float4 b1 = *(const float4*)(Bp + k0);
    const float4 b2 = *(const float4*)(Bp + k0 + 4);
    __syncthreads();
    *(short8v*)&As[sr][seg * 8] = cvt8(a1, a2);
    *(short8v*)&Bs[sr][seg * 8] = cvt8(b1, b2);
    __syncthreads();
    short8v af[2], bf[2];
#pragma unroll
    for (int mi = 0; mi < 2; ++mi)
      af[mi] = *(const short8v*)&As[wr * 32 + mi * 16 + c][g * 8];
#pragma unroll
    for (int ni = 0; ni < 2; ++ni)
      bf[ni] = *(const short8v*)&Bs[wc * 32 + ni * 16 + c][g * 8];
#pragma unroll
    for (int mi = 0; mi < 2; ++mi)
#pragma unroll
      for (int ni = 0; ni < 2; ++ni)
        acc[mi][ni] = __builtin_amdgcn_mfma_f32_16x16x32_bf16(
            af[mi], bf[ni], acc[mi][ni], 0, 0, 0);
  }
#pragma unroll
  for (int mi = 0; mi < 2; ++mi) {
#pragma unroll
    for (int ni = 0; ni < 2; ++ni) {
      const int col = n0 + wc * 32 + ni * 16 + c;
      const float bb = bias[col];
      if (sel == 2) {
        // V^T swizzled: token mb..mb+3 -> chunkbase + p(mb) + 0..3
        const int mb = m0 + wr * 32 + mi * 16 + g * 4;
        const int pidx = (mb & ~31) + ((mb >> 4) & 1) * 4 + ((mb >> 2) & 3) * 8;
        uint2 pk;
        const float v0 = acc[mi][ni][0] + bb, v1 = acc[mi][ni][1] + bb;
        const float v2 = acc[mi][ni][2] + bb, v3 = acc[mi][ni][3] + bb;
        pk.x = (unsigned)(unsigned short)bfr(v0) | ((unsigned)(unsigned short)bfr(v1) << 16);
        pk.y = (unsigned)(unsigned short)bfr(v2) | ((unsigned)(unsigned short)bfr(v3) << 16);
        *(uint2*)&VT[(size_t)col * N_TOK + pidx] = pk;
      } else {
        short* Ct = (sel == 0) ? QB : KB;
        const float qs = (sel == 0) ? QSC : 1.f;
#pragma unroll
        for (int q = 0; q < 4; ++q) {
          const int m = m0 + wr * 32 + mi * 16 + g * 4 + q;
          Ct[(size_t)m * CD + col] = bfr((acc[mi][ni][q] + bb) * qs);
        }
      }
    }
  }
}

// ------------------------- Gram G = X X^T via split-bf16 (hi+lo) MFMA
__global__ __launch_bounds__(256) void gemm_syr2_k(const float* __restrict__ A,
    float* __restrict__ C) {
  __shared__ __align__(16) short AsH[64][40];
  __shared__ __align__(16) short AsL[64][40];
  __shared__ __align__(16) short BsH[64][40];
  __shared__ __align__(16) short BsL[64][40];
  int bid = blockIdx.x;
  int bi = (int)((sqrtf(8.f * (float)bid + 1.f) - 1.f) * 0.5f);
  while ((bi + 1) * (bi + 2) / 2 <= bid) ++bi;
  while (bi * (bi + 1) / 2 > bid) --bi;
  const int bj = bid - bi * (bi + 1) / 2;
  const int m0 = bi * 64, n0 = bj * 64;
  const int t = threadIdx.x;
  const int w = t >> 6, l = t & 63;
  const int g = l >> 4, c = l & 15;
  const int wr = w >> 1, wc = w & 1;
  const int sr = t >> 2, seg = t & 3;
  const float* Ap = A + (size_t)(m0 + sr) * CD + seg * 8;
  const float* Bp = A + (size_t)(n0 + sr) * CD + seg * 8;
  f32x4 acc[2][2] = {};
  for (int k0 = 0; k0 < CD; k0 += 32) {
    const float4 a1 = *(const float4*)(Ap + k0);
    const float4 a2 = *(const float4*)(Ap + k0 + 4);
    const float4 b1 = *(const float4*)(Bp + k0);
    const float4 b2 = *(const float4*)(Bp + k0 + 4);
    __syncthreads();
    short8v h8, l8;
    split8(a1, a2, h8, l8);
    *(short8v*)&AsH[sr][seg * 8] = h8;
    *(short8v*)&AsL[sr][seg * 8] = l8;
    split8(b1, b2, h8, l8);
    *(short8v*)&BsH[sr][seg * 8] = h8;
    *(short8v*)&BsL[sr][seg * 8] = l8;
    __syncthreads();
    short8v afH[2], afL[2], bfH[2], bfL[2];
#pragma unroll
    for (int mi = 0; mi < 2; ++mi) {
      afH[mi] = *(const short8v*)&AsH[wr * 32 + mi * 16 + c][g * 8];
      afL[mi] = *(const short8v*)&AsL[wr * 32 + mi * 16 + c][g * 8];
    }
#pragma unroll
    for (int ni = 0; ni < 2; ++ni) {
      bfH[ni] = *(const short8v*)&BsH[wc * 32 + ni * 16 + c][g * 8];
      bfL[ni] = *(const short8v*)&BsL[wc * 32 + ni * 16 + c][g * 8];
    }
#pragma unroll
    for (int mi = 0; mi < 2; ++mi)
#pragma unroll
      for (int ni = 0; ni < 2; ++ni) {
        acc[mi][ni] = __builtin_amdgcn_mfma_f32_16x16x32_bf16(afH[mi], bfH[ni], acc[mi][ni], 0, 0, 0);
        acc[mi][ni] = __builtin_amdgcn_mfma_f32_16x16x32_bf16(afH[mi], bfL[ni], acc[mi][ni], 0, 0, 0);
        acc[mi][ni] = __builtin_amdgcn_mfma_f32_16x16x32_bf16(afL[mi], bfH[ni], acc[mi][ni], 0, 0, 0);
      }
  }
#pragma unroll
  for (int mi = 0; mi < 2; ++mi)
#pragma unroll
    for (int ni = 0; ni < 2; ++ni) {
      const int col = n0 + wc * 32 + ni * 16 + c;
#pragma unroll
      for (int q = 0; q < 4; ++q) {
        const int m = m0 + wr * 32 + mi * 16 + g * 4 + q;
        const float v = acc[mi][ni][q];
        C[(size_t)m * N_TOK + col] = v;
        C[(size_t)col * N_TOK + m] = v;
      }
    }
}

// ------------------------------------------------------------ conv2 (8ch)
__global__ __launch_bounds__(256) void conv2_k(const float* __restrict__ t1,
    const float* __restrict__ w, const float* __restrict__ b,
    float* __restrict__ gp) {
  __shared__ float ws3[9 * 8 * 132];
  const int t = threadIdx.x;
  for (int e = t; e < 9216; e += 256) {
    int r = e >> 10;
    int rem = e & 1023;
    int co = rem >> 7;
    int ci = rem & 127;
    ws3[(r * 8 + co) * 132 + ci] = w[((size_t)co * 128 + ci) * 9 + r];
  }
  __syncthreads();
  const int pix = blockIdx.x * 32 + (t >> 3);
  const int co = t & 7;
  const int y = pix / 56, x = pix - y * 56;
  float acc = b[co];
  for (int ky = 0; ky < 3; ++ky) {
    int yy = y + ky - 1;
    if (yy < 0 || yy >= 56) continue;
    for (int kx = 0; kx < 3; ++kx) {
      int xx = x + kx - 1;
      if (xx < 0 || xx >= 56) continue;
      const float4* tp = (const float4*)&t1[(size_t)(yy * 56 + xx) * 128];
      const float* wp = &ws3[((ky * 3 + kx) * 8 + co) * 132];
#pragma unroll
      for (int c4 = 0; c4 < 32; ++c4) {
        const float4 tv = tp[c4];
        const float4 wv = *(const float4*)&wp[c4 * 4];
        acc += tv.x * wv.x + tv.y * wv.y + tv.z * wv.z + tv.w * wv.w;
      }
    }
  }
  gp[pix * 8 + co] = 1.f / (1.f + expf(-acc));
}

// ------------------------------------------------------------- row ||x||^2
__global__ __launch_bounds__(64) void rowsq_k(const float* __restrict__ x,
                                              float* __restrict__ sq) {
  const int i = blockIdx.x, lane = threadIdx.x;
  const float4 v = ((const float4*)&x[(size_t)i * CD])[lane];
  float s = v.x * v.x + v.y * v.y + v.z * v.z + v.w * v.w;
#pragma unroll
  for (int m = 1; m < 64; m <<= 1) s += __shfl_xor(s, m, 64);
  if (lane == 0) sq[i] = s;
}

// -------------------------------------------------- top-16 NN + in-degree
__global__ __launch_bounds__(256) void topk_k(const float* __restrict__ G,
    const float* __restrict__ sq, int* __restrict__ near) {
  __shared__ unsigned long long wmin[4];
  const int i = blockIdx.x;
  const int t = threadIdx.x;
  const float sqi = sq[i];
  unsigned long long key[13];
#pragma unroll
  for (int e = 0; e < 13; ++e) {
    int j = t + (e << 8);
    float d2 = INFINITY;
    if (j < N_TOK) d2 = (sqi - 2.f * G[(size_t)i * N_TOK + j]) + sq[j];
    key[e] = ((unsigned long long)f2mono(d2) << 32) | (unsigned)j;
  }
  unsigned long long last = 0ull;
#pragma unroll 1
  for (int r = 0; r < 16; ++r) {
    unsigned long long best = ~0ull;
#pragma unroll
    for (int e = 0; e < 13; ++e) {
      bool ok = (key[e] > last) && (key[e] < best);
      best = ok ? key[e] : best;
    }
#pragma unroll
    for (int m = 1; m < 64; m <<= 1) {
      unsigned long long o = sx64(best, m);
      best = (o < best) ? o : best;
    }
    __syncthreads();
    if ((t & 63) == 0) wmin[t >> 6] = best;
    __syncthreads();
    unsigned long long b0 = wmin[0] < wmin[1] ? wmin[0] : wmin[1];
    unsigned long long b1 = wmin[2] < wmin[3] ? wmin[2] : wmin[3];
    best = b0 < b1 ? b0 : b1;
    if (t == 0) atomicAdd(&near[(unsigned)(best & 0xffffffffu)], 1);
    last = best;
  }
}

// ------------------------------------------------------------- max(near)
__global__ __launch_bounds__(256) void nearmax_k(const int* __restrict__ near,
                                                 int* __restrict__ nmax) {
  __shared__ int sm[4];
  const int t = threadIdx.x;
  int m = 0;
  for (int j = t; j < N_TOK; j += 256) m = max(m, near[j]);
#pragma unroll
  for (int s = 1; s < 64; s <<= 1) m = max(m, __shfl_xor(m, s, 64));
  if ((t & 63) == 0) sm[t >> 6] = m;
  __syncthreads();
  if (t == 0) nmax[0] = max(max(sm[0], sm[1]), max(sm[2], sm[3]));
}

// ------------------------------------------------ qk_in = x + emb[ni(near)]
__global__ __launch_bounds__(256) void qkin_k(const float* __restrict__ x,
    const int* __restrict__ near, const int* __restrict__ nmax,
    const float* __restrict__ emb, float* __restrict__ qkin) {
  const int i = blockIdx.x, t = threadIdx.x;
  const float nf = (float)near[i], mf = (float)nmax[0];
  const int ni = (int)(nf / mf * 9.0f);
  qkin[(size_t)i * CD + t] = x[(size_t)i * CD + t] + emb[ni * CD + t];
}

// ---------------------------------- gp [tok][8] -> gpT [8][tok], * log2e
__global__ __launch_bounds__(256) void gpt_k(const float* __restrict__ gp,
                                             float* __restrict__ gpT) {
  const int e = blockIdx.x * 256 + threadIdx.x;
  const int i = e >> 3, h = e & 7;
  gpT[h * N_TOK + i] = gp[e] * LOG2E;
}

// ---- flash attention v5: 32 queries/block shared by 4 j-quarter waves
// grid (98, 8). Each wave: 2 query groups (16 cols each), slot-aligned PV,
// defer-max, K prefetch. In-block LDS combine writes normalized O directly.
__global__ __launch_bounds__(256) void attn_v5_k(const short* __restrict__ Qb,
    const short* __restrict__ Kb, const short* __restrict__ Vt,
    const float* __restrict__ gpT, float* __restrict__ O1) {
  __shared__ float o_l[4][32][36];
  __shared__ float ml_l[4][32][2];
  const int h = blockIdx.y;
  const int qb = blockIdx.x * 32;
  const int t = threadIdx.x;
  const int w = t >> 6, l = t & 63;
  const int g = l >> 4, c = l & 15;
  const size_t hoff = (size_t)h * DH;
  short8v qf[2];
  float gpi[2];
#pragma unroll
  for (int gr = 0; gr < 2; ++gr) {
    qf[gr] = *(const short8v*)&Qb[(size_t)(qb + gr * 16 + c) * CD + hoff + g * 8];
    gpi[gr] = gpT[h * N_TOK + qb + gr * 16 + c];
  }
  const int jt0 = w ? (13 + 12 * (w - 1)) : 0;
  const int jt1 = jt0 + (w ? 13 : 13) - (w ? 1 : 0);  // {13,12,12,12} tiles
  float mr[2] = {-INFINITY, -INFINITY};
  float lp[2] = {0.f, 0.f};
  f32x4 oa[2][2] = {};
  const f32x4 zz = {0.f, 0.f, 0.f, 0.f};

  short8v kf[4];
#pragma unroll
  for (int sub = 0; sub < 4; ++sub)
    kf[sub] = *(const short8v*)&Kb[(size_t)(jt0 * 64 + sub * 16 + c) * CD + hoff + g * 8];

  for (int jt = jt0; jt < jt1; ++jt) {
    const int j0 = jt * 64;
    // QK^T both groups: s[gr][sub][q] = S[slot sub*16+g*4+q][query gr*16+c]
    f32x4 s[2][4];
#pragma unroll
    for (int sub = 0; sub < 4; ++sub) {
      s[0][sub] = __builtin_amdgcn_mfma_f32_16x16x32_bf16(kf[sub], qf[0], zz, 0, 0, 0);
      s[1][sub] = __builtin_amdgcn_mfma_f32_16x16x32_bf16(kf[sub], qf[1], zz, 0, 0, 0);
    }
    // V fragments (shared by both groups), issued before softmax
    short8v vf[4];
#pragma unroll
    for (int ch = 0; ch < 2; ++ch)
#pragma unroll
      for (int ds = 0; ds < 2; ++ds)
        vf[ch * 2 + ds] = *(const short8v*)&Vt[(hoff + ds * 16 + c) * (size_t)N_TOK + j0 + ch * 32 + g * 8];
    // prefetch next K tile (kf dead after the QK above)
    if (jt + 1 < jt1) {
#pragma unroll
      for (int sub = 0; sub < 4; ++sub)
        kf[sub] = *(const short8v*)&Kb[(size_t)(j0 + 64 + sub * 16 + c) * CD + hoff + g * 8];
    }
    float4 gj[4];
#pragma unroll
    for (int sub = 0; sub < 4; ++sub)
      gj[sub] = *(const float4*)&gpT[h * N_TOK + j0 + sub * 16 + g * 4];
#pragma unroll
    for (int gr = 0; gr < 2; ++gr) {
      // bias (log2 domain)
      float sv[16];
#pragma unroll
      for (int sub = 0; sub < 4; ++sub) {
        sv[sub * 4 + 0] = s[gr][sub][0] + fabsf(gpi[gr] - gj[sub].x);
        sv[sub * 4 + 1] = s[gr][sub][1] + fabsf(gpi[gr] - gj[sub].y);
        sv[sub * 4 + 2] = s[gr][sub][2] + fabsf(gpi[gr] - gj[sub].z);
        sv[sub * 4 + 3] = s[gr][sub][3] + fabsf(gpi[gr] - gj[sub].w);
      }
      // lane-local tree max
      float a0 = fmaxf(sv[0], sv[1]),  a1 = fmaxf(sv[2], sv[3]);
      float a2 = fmaxf(sv[4], sv[5]),  a3 = fmaxf(sv[6], sv[7]);
      float a4 = fmaxf(sv[8], sv[9]),  a5 = fmaxf(sv[10], sv[11]);
      float a6 = fmaxf(sv[12], sv[13]), a7 = fmaxf(sv[14], sv[15]);
      const float mx = fmaxf(fmaxf(fmaxf(a0, a1), fmaxf(a2, a3)),
                             fmaxf(fmaxf(a4, a5), fmaxf(a6, a7)));
      // defer-max rebase (rare)
      if (!__all(mx - mr[gr] <= 11.f)) {
        float mn = mx;
        mn = fmaxf(mn, __shfl_xor(mn, 16, 64));
        mn = fmaxf(mn, __shfl_xor(mn, 32, 64));
        mn = fmaxf(mn, mr[gr]);
        const float sc = __builtin_amdgcn_exp2f(mr[gr] - mn);
        oa[gr][0][0] *= sc; oa[gr][0][1] *= sc; oa[gr][0][2] *= sc; oa[gr][0][3] *= sc;
        oa[gr][1][0] *= sc; oa[gr][1][1] *= sc; oa[gr][1][2] *= sc; oa[gr][1][3] *= sc;
        lp[gr] *= sc;
        mr[gr] = mn;
      }
      // exp2 + truncate to bf16 (consistent for l-sum and PV)
      unsigned pu[16];
      float pvt[16];
#pragma unroll
      for (int e = 0; e < 16; ++e) {
        const float p = __builtin_amdgcn_exp2f(sv[e] - mr[gr]);
        pu[e] = __float_as_uint(p) & 0xffff0000u;
        pvt[e] = __uint_as_float(pu[e]);
      }
      const float s0 = (pvt[0] + pvt[1]) + (pvt[2] + pvt[3]);
      const float s1 = (pvt[4] + pvt[5]) + (pvt[6] + pvt[7]);
      const float s2 = (pvt[8] + pvt[9]) + (pvt[10] + pvt[11]);
      const float s3 = (pvt[12] + pvt[13]) + (pvt[14] + pvt[15]);
      lp[gr] += (s0 + s1) + (s2 + s3);
      // pack P pairs
      unsigned pk8[8];
#pragma unroll
      for (int sub = 0; sub < 4; ++sub) {
        pk8[2 * sub + 0] = __builtin_amdgcn_perm(pu[4 * sub + 1], pu[4 * sub + 0], 0x07060302u);
        pk8[2 * sub + 1] = __builtin_amdgcn_perm(pu[4 * sub + 3], pu[4 * sub + 2], 0x07060302u);
      }
      union { unsigned u[4]; short8v s; } pf0, pf1;
      pf0.u[0] = pk8[0]; pf0.u[1] = pk8[1]; pf0.u[2] = pk8[2]; pf0.u[3] = pk8[3];
      pf1.u[0] = pk8[4]; pf1.u[1] = pk8[5]; pf1.u[2] = pk8[6]; pf1.u[3] = pk8[7];
      // PV: O^T[d][query]; k-enum = slot order, P frag = own registers
      oa[gr][0] = __builtin_amdgcn_mfma_f32_16x16x32_bf16(vf[0], pf0.s, oa[gr][0], 0, 0, 0);
      oa[gr][1] = __builtin_amdgcn_mfma_f32_16x16x32_bf16(vf[1], pf0.s, oa[gr][1], 0, 0, 0);
      oa[gr][0] = __builtin_amdgcn_mfma_f32_16x16x32_bf16(vf[2], pf1.s, oa[gr][0], 0, 0, 0);
      oa[gr][1] = __builtin_amdgcn_mfma_f32_16x16x32_bf16(vf[3], pf1.s, oa[gr][1], 0, 0, 0);
    }
  }
  // ---- per-wave partials to LDS
#pragma unroll
  for (int gr = 0; gr < 2; ++gr) {
    lp[gr] += __shfl_xor(lp[gr], 16, 64);
    lp[gr] += __shfl_xor(lp[gr], 32, 64);
#pragma unroll
    for (int ds = 0; ds < 2; ++ds)
      *(f32x4*)&o_l[w][gr * 16 + c][ds * 16 + g * 4] = oa[gr][ds];
    if (g == 0) {
      ml_l[w][gr * 16 + c][0] = mr[gr];
      ml_l[w][gr * 16 + c][1] = lp[gr];
    }
  }
  __syncthreads();
  // ---- combine 4 quarters: thread -> (q = t>>3, d0 = (t&7)*4)
  const int q = t >> 3, d0 = (t & 7) * 4;
  const float M = fmaxf(fmaxf(ml_l[0][q][0], ml_l[1][q][0]),
                        fmaxf(ml_l[2][q][0], ml_l[3][q][0]));
  float den = 0.f;
  f32x4 num = {0.f, 0.f, 0.f, 0.f};
#pragma unroll
  for (int sp = 0; sp < 4; ++sp) {
    const float wg = __builtin_amdgcn_exp2f(ml_l[sp][q][0] - M);
    den += wg * ml_l[sp][q][1];
    const f32x4 ov = *(const f32x4*)&o_l[sp][q][d0];
    num[0] += wg * ov[0]; num[1] += wg * ov[1];
    num[2] += wg * ov[2]; num[3] += wg * ov[3];
  }
  const float inv = 1.f / den;
  f32x4 r = {num[0] * inv, num[1] * inv, num[2] * inv, num[3] * inv};
  *(f32x4*)&O1[(size_t)(qb + q) * CD + hoff + d0] = r;
}

// ---------------------- LayerNorm (+residual) (+optional row-sq output)
__global__ __launch_bounds__(256) void ln_k(const float* __restrict__ xin,
    const float* __restrict__ add, const float* __restrict__ g,
    const float* __restrict__ b, float* __restrict__ xout,
    float* __restrict__ sqout) {
  __shared__ float red1[4];
  __shared__ float red2[4];
  const int i = blockIdx.x, t = threadIdx.x;
  float v = xin[(size_t)i * CD + t];
  if (add) v += add[(size_t)i * CD + t];
  float s = v;
#pragma unroll
  for (int m = 1; m < 64; m <<= 1) s += __shfl_xor(s, m, 64);
  if ((t & 63) == 0) red1[t >> 6] = s;
  __syncthreads();
  const float mean = (red1[0] + red1[1] + red1[2] + red1[3]) * (1.f / 256.f);
  const float d = v - mean;
  float s2 = d * d;
#pragma unroll
  for (int m = 1; m < 64; m <<= 1) s2 += __shfl_xor(s2, m, 64);
  if ((t & 63) == 0) red2[t >> 6] = s2;
  __syncthreads();
  const float var = (red2[0] + red2[1] + red2[2] + red2[3]) * (1.f / 256.f);
  const float xo = d * rsqrtf(var + 1e-5f) * g[t] + b[t];
  xout[(size_t)i * CD + t] = xo;
  if (sqout) {
    float s3 = xo * xo;
#pragma unroll
    for (int m = 1; m < 64; m <<= 1) s3 += __shfl_xor(s3, m, 64);
    __syncthreads();
    if ((t & 63) == 0) red1[t >> 6] = s3;
    __syncthreads();
    if (t == 0) sqout[i] = red1[0] + red1[1] + red1[2] + red1[3];
  }
}

// ---------------------------------------------------------------- launch
extern "C" void kernel_launch(void* const* d_in, const int* in_sizes, int n_in,
                              void* d_out, int out_size, void* d_ws, size_t ws_size,
                              hipStream_t stream) {
  const float* src  = (const float*)d_in[0];
  const float* c1w  = (const float*)d_in[1];
  const float* c1b  = (const float*)d_in[2];
  const float* c2w  = (const float*)d_in[3];
  const float* c2b  = (const float*)d_in[4];
  const float* nemb = (const float*)d_in[5];
  const float* Wq   = (const float*)d_in[6];
  const float* bq   = (const float*)d_in[7];
  const float* Wk   = (const float*)d_in[8];
  const float* bk   = (const float*)d_in[9];
  const float* Wv   = (const float*)d_in[10];
  const float* bv   = (const float*)d_in[11];
  const float* Wo   = (const float*)d_in[12];
  const float* bo   = (const float*)d_in[13];
  const float* W1   = (const float*)d_in[14];
  const float* b1   = (const float*)d_in[15];
  const float* W2   = (const float*)d_in[16];
  const float* b2   = (const float*)d_in[17];
  const float* ln1g = (const float*)d_in[18];
  const float* ln1b = (const float*)d_in[19];
  const float* ln2g = (const float*)d_in[20];
  const float* ln2b = (const float*)d_in[21];
  const float* ng   = (const float*)d_in[22];
  const float* nb   = (const float*)d_in[23];

  float* ws = (float*)d_ws;
  const size_t NC = (size_t)N_TOK * CD;          // 802816
  float* X    = ws;
  float* QKIN = X + NC;
  float* O1   = QKIN + NC;
  float* TMP  = O1 + NC;
  float* FF1  = TMP + NC;                        // 3136*1024
  float* G    = FF1 + (size_t)N_TOK * DFFD;      // 3136*3136 (also im2col)
  float* T1   = G + (size_t)N_TOK * N_TOK;       // 3136*128
  float* GP   = T1 + (size_t)N_TOK * 128;        // 3136*8
  float* GPT  = GP + (size_t)N_TOK * NHD;        // 3136*8
  float* SQF  = GPT + (size_t)N_TOK * NHD;       // 3136
  short* QB16 = (short*)(SQF + N_TOK);
  short* KB16 = QB16 + NC;
  short* VT16 = KB16 + NC;
  int*   NEAR = (int*)(VT16 + NC);
  int*   NMAX = NEAR + N_TOK;

  // conv positional encoder
  im2col_k<<<28224, 256, 0, stream>>>(src, G);
  gemm_bt_bf16<1><<<dim3(2, 49), 256, 0, stream>>>(G, c1w, c1b, T1, N_TOK, 128, 2304);
  conv2_k<<<98, 256, 0, stream>>>(T1, c2w, c2b, GP);
  gpt_k<<<98, 256, 0, stream>>>(GP, GPT);
  transpose_k<<<dim3(98, 8), 256, 0, stream>>>(src, X, 256, N_TOK);
  rowsq_k<<<N_TOK, 64, 0, stream>>>(X, SQF);

  for (int l = 0; l < 4; ++l) {
    // ---- kNN graph -> near counts (split-bf16 MFMA Gram)
    gemm_syr2_k<<<1225, 256, 0, stream>>>(X, G);
    (void)hipMemsetAsync(NEAR, 0, N_TOK * sizeof(int), stream);
    topk_k<<<N_TOK, 256, 0, stream>>>(G, SQF, NEAR);
    nearmax_k<<<1, 256, 0, stream>>>(NEAR, NMAX);
    qkin_k<<<N_TOK, 256, 0, stream>>>(X, NEAR, NMAX, nemb, QKIN);
    // ---- fused Q/K/V projections (Q pre-scaled log2 domain, V^T swizzled)
    proj_qkv_k<<<dim3(12, 49), 256, 0, stream>>>(QKIN, X,
        Wq + (size_t)l * 65536, Wk + (size_t)l * 65536, Wv + (size_t)l * 65536,
        bq + l * 256, bk + l * 256, bv + l * 256, QB16, KB16, VT16);
    // ---- attention (shared K/V across 4 j-quarter waves, in-block combine)
    attn_v5_k<<<dim3(98, 8), 256, 0, stream>>>(QB16, KB16, VT16, GPT, O1);
    gemm_bt_bf16<0><<<dim3(4, 49), 256, 0, stream>>>(O1, Wo + (size_t)l * 65536, bo + l * 256, TMP, N_TOK, CD, CD);
    ln_k<<<N_TOK, 256, 0, stream>>>(X, TMP, ln1g + l * 256, ln1b + l * 256, X, nullptr);
    // ---- FFN
    gemm_bt_bf16<1><<<dim3(16, 49), 256, 0, stream>>>(X, W1 + (size_t)l * 262144, b1 + l * 1024, FF1, N_TOK, DFFD, CD);
    gemm_bt_bf16<0><<<dim3(4, 49), 256, 0, stream>>>(FF1, W2 + (size_t)l * 262144, b2 + l * 256, TMP, N_TOK, CD, DFFD);
    ln_k<<<N_TOK, 256, 0, stream>>>(X, TMP, ln2g + l * 256, ln2b + l * 256, X, SQF);
  }
  // final LN + transpose to [1,C,H,W]
  ln_k<<<N_TOK, 256, 0, stream>>>(X, nullptr, ng, nb, TMP, nullptr);
  transpose_k<<<dim3(8, 98), 256, 0, stream>>>(TMP, (float*)d_out, N_TOK, 256);
}

// Round 8
// 830.329 us; speedup vs baseline: 3.1144x; 1.1503x over previous
//
#include <hip/hip_runtime.h>
#include <math.h>

#define N_TOK 3136
#define CD    256
#define NHD   8
#define DH    32
#define DFFD  1024
#define SCALE 0.17677669529663687f  /* 32^-0.5 */
#define LOG2E 1.4426950408889634f
#define QSC   (SCALE * LOG2E)

typedef __attribute__((ext_vector_type(8))) short short8v;
typedef __attribute__((ext_vector_type(4))) float f32x4;

// ---------------------------------------------------------------- utils
__device__ __forceinline__ unsigned long long sx64(unsigned long long v, int m) {
  unsigned lo = (unsigned)__shfl_xor((int)(unsigned)(v & 0xffffffffull), m, 64);
  unsigned hi = (unsigned)__shfl_xor((int)(unsigned)(v >> 32), m, 64);
  return ((unsigned long long)hi << 32) | lo;
}

__device__ __forceinline__ unsigned f2mono(float v) {
  unsigned b = __float_as_uint(v);
  return (b & 0x80000000u) ? ~b : (b | 0x80000000u);
}

// fp32 -> bf16 round-to-nearest-even
__device__ __forceinline__ short bfr(float f) {
  unsigned u = __float_as_uint(f);
  unsigned r = (u + 0x7fffu + ((u >> 16) & 1u)) >> 16;
  return (short)r;
}

__device__ __forceinline__ short8v cvt8(float4 a, float4 b) {
  short8v r;
  r[0] = bfr(a.x); r[1] = bfr(a.y); r[2] = bfr(a.z); r[3] = bfr(a.w);
  r[4] = bfr(b.x); r[5] = bfr(b.y); r[6] = bfr(b.z); r[7] = bfr(b.w);
  return r;
}

// split fp32 into bf16 hi (truncate) + bf16 lo (truncate of remainder)
__device__ __forceinline__ void split8(float4 a, float4 b, short8v& hi, short8v& lo) {
  const float f[8] = {a.x, a.y, a.z, a.w, b.x, b.y, b.z, b.w};
#pragma unroll
  for (int u = 0; u < 8; ++u) {
    const unsigned ui = __float_as_uint(f[u]);
    hi[u] = (short)(ui >> 16);
    const float hf = __uint_as_float(ui & 0xffff0000u);
    lo[u] = (short)(__float_as_uint(f[u] - hf) >> 16);
  }
}

// ------------------------------------------------- transpose (32x32 tiles)
__global__ __launch_bounds__(256) void transpose_k(const float* __restrict__ in,
    float* __restrict__ out, int R, int C) {
  __shared__ float ls[32][33];
  const int c0 = blockIdx.x * 32, r0 = blockIdx.y * 32;
  const int tx = threadIdx.x & 31, ty = threadIdx.x >> 5;
#pragma unroll
  for (int j = 0; j < 4; ++j) {
    int r = ty + j * 8;
    ls[r][tx] = in[(size_t)(r0 + r) * C + c0 + tx];
  }
  __syncthreads();
#pragma unroll
  for (int j = 0; j < 4; ++j) {
    int cc = ty + j * 8;
    out[(size_t)(c0 + cc) * R + r0 + tx] = ls[tx][cc];
  }
}

// -------------------- conv1 weight transpose: WT[r][co][ci] = w[co][ci][r]
__global__ __launch_bounds__(256) void wtr_k(const float* __restrict__ w,
                                             float* __restrict__ wt) {
  const int e = blockIdx.x * 256 + threadIdx.x;   // < 9*128*256 = 294912
  const int r = e >> 15;
  const int rem = e & 32767;
  const int co = rem >> 8, ci = rem & 255;
  wt[e] = w[((size_t)co * 256 + ci) * 9 + r];
}

// -------- conv1 as direct tap-GEMM: grid (2, 98, 3), z = ky; 32-pixel tiles
// P[ky][pix][co] = sum_{kx,ci} X[shift(pix,ky,kx)][ci] * WT[ky*3+kx][co][ci]
__global__ __launch_bounds__(256) void conv1_k(const float* __restrict__ X,
    const float* __restrict__ WT, float* __restrict__ P) {
  __shared__ __align__(16) short As[32][40];
  __shared__ __align__(16) short Bs[64][40];
  const int n0 = blockIdx.x * 64;
  const int m0 = blockIdx.y * 32;
  const int ky = blockIdx.z;
  const int t = threadIdx.x;
  const int w = t >> 6, l = t & 63;
  const int g = l >> 4, c = l & 15;
  const int wr = w >> 1, wc = w & 1;
  const int sr = t >> 2, seg = t & 3;       // B rows 0..63; A rows = sr (t<128)
  const int p = m0 + (sr & 31);
  const int y = p / 56, x = p - y * 56;
  const int yy = y + ky - 1;
  f32x4 acc[2] = {};
  for (int kx = 0; kx < 3; ++kx) {
    const int xx = x + kx - 1;
    const bool valid = (t < 128) && ((unsigned)yy < 56u) && ((unsigned)xx < 56u);
    const float* Ap = X + (size_t)(yy * 56 + xx) * CD + seg * 8;
    const float* Bp = WT + ((size_t)(ky * 3 + kx) * 128 + n0 + sr) * CD + seg * 8;
    for (int k0 = 0; k0 < CD; k0 += 32) {
      float4 a1 = make_float4(0.f, 0.f, 0.f, 0.f), a2 = a1;
      if (valid) { a1 = *(const float4*)(Ap + k0); a2 = *(const float4*)(Ap + k0 + 4); }
      const float4 b1 = *(const float4*)(Bp + k0);
      const float4 b2 = *(const float4*)(Bp + k0 + 4);
      __syncthreads();
      if (t < 128) *(short8v*)&As[sr][seg * 8] = cvt8(a1, a2);
      *(short8v*)&Bs[sr][seg * 8] = cvt8(b1, b2);
      __syncthreads();
      const short8v af = *(const short8v*)&As[wr * 16 + c][g * 8];
      const short8v bf0 = *(const short8v*)&Bs[wc * 32 + c][g * 8];
      const short8v bf1 = *(const short8v*)&Bs[wc * 32 + 16 + c][g * 8];
      acc[0] = __builtin_amdgcn_mfma_f32_16x16x32_bf16(af, bf0, acc[0], 0, 0, 0);
      acc[1] = __builtin_amdgcn_mfma_f32_16x16x32_bf16(af, bf1, acc[1], 0, 0, 0);
    }
  }
#pragma unroll
  for (int ni = 0; ni < 2; ++ni) {
    const int col = n0 + wc * 32 + ni * 16 + c;
#pragma unroll
    for (int q = 0; q < 4; ++q) {
      const int m = m0 + wr * 16 + g * 4 + q;
      P[((size_t)ky * N_TOK + m) * 128 + col] = acc[ni][q];
    }
  }
}

// ----------------------- reduce conv1 tap partials + bias + relu -> T1
__global__ __launch_bounds__(256) void convred_k(const float* __restrict__ P,
    const float* __restrict__ b, float* __restrict__ T1) {
  const int e = blockIdx.x * 256 + threadIdx.x;   // < 3136*128
  const float v = P[e] + P[401408 + e] + P[802816 + e] + b[e & 127];
  T1[e] = fmaxf(v, 0.f);
}

// ------------------ 32x64-tile bf16 MFMA GEMM NT (fp32 in, fp32 out)
// grid (N/64, 98). C[m][n] = sum_k A[m][k]*B[n][k] (+bias)(+relu).
template <int RELU>
__global__ __launch_bounds__(256) void gemm32_k(const float* __restrict__ A,
    const float* __restrict__ B, const float* __restrict__ bias,
    float* __restrict__ C, int N, int K) {
  __shared__ __align__(16) short As[32][40];
  __shared__ __align__(16) short Bs[64][40];
  const int n0 = blockIdx.x * 64;
  const int m0 = blockIdx.y * 32;
  const int t = threadIdx.x;
  const int w = t >> 6, l = t & 63;
  const int g = l >> 4, c = l & 15;
  const int wr = w >> 1, wc = w & 1;
  const int sr = t >> 2, seg = t & 3;
  const float* Ap = A + (size_t)(m0 + (sr & 31)) * K + seg * 8;
  const float* Bp = B + (size_t)(n0 + sr) * K + seg * 8;
  f32x4 acc[2] = {};
  for (int k0 = 0; k0 < K; k0 += 32) {
    float4 a1 = make_float4(0.f, 0.f, 0.f, 0.f), a2 = a1;
    if (t < 128) { a1 = *(const float4*)(Ap + k0); a2 = *(const float4*)(Ap + k0 + 4); }
    const float4 b1 = *(const float4*)(Bp + k0);
    const float4 b2 = *(const float4*)(Bp + k0 + 4);
    __syncthreads();
    if (t < 128) *(short8v*)&As[sr][seg * 8] = cvt8(a1, a2);
    *(short8v*)&Bs[sr][seg * 8] = cvt8(b1, b2);
    __syncthreads();
    const short8v af = *(const short8v*)&As[wr * 16 + c][g * 8];
    const short8v bf0 = *(const short8v*)&Bs[wc * 32 + c][g * 8];
    const short8v bf1 = *(const short8v*)&Bs[wc * 32 + 16 + c][g * 8];
    acc[0] = __builtin_amdgcn_mfma_f32_16x16x32_bf16(af, bf0, acc[0], 0, 0, 0);
    acc[1] = __builtin_amdgcn_mfma_f32_16x16x32_bf16(af, bf1, acc[1], 0, 0, 0);
  }
#pragma unroll
  for (int ni = 0; ni < 2; ++ni) {
    const int col = n0 + wc * 32 + ni * 16 + c;
    const float bb = bias ? bias[col] : 0.f;
#pragma unroll
    for (int q = 0; q < 4; ++q) {
      const int m = m0 + wr * 16 + g * 4 + q;
      float v = acc[ni][q] + bb;
      if (RELU) v = fmaxf(v, 0.f);
      C[(size_t)m * N + col] = v;
    }
  }
}

// ---------------- fused Q/K/V projections, 32-row tiles, bf16 outputs
// grid (4, 98, 3): z = sel (0=Q,1=K,2=V). Q scaled QSC; V^T chunk-swizzled.
__global__ __launch_bounds__(256) void proj32_k(const float* __restrict__ QKIN,
    const float* __restrict__ X, const float* __restrict__ Wq,
    const float* __restrict__ Wk, const float* __restrict__ Wv,
    const float* __restrict__ bq, const float* __restrict__ bk,
    const float* __restrict__ bv, short* __restrict__ QB,
    short* __restrict__ KB, short* __restrict__ VT) {
  __shared__ __align__(16) short As[32][40];
  __shared__ __align__(16) short Bs[64][40];
  const int sel = blockIdx.z;
  const int n0 = blockIdx.x * 64;
  const int m0 = blockIdx.y * 32;
  const float* A = (sel < 2) ? QKIN : X;
  const float* B = (sel == 0) ? Wq : (sel == 1) ? Wk : Wv;
  const float* bias = (sel == 0) ? bq : (sel == 1) ? bk : bv;
  const int t = threadIdx.x;
  const int w = t >> 6, l = t & 63;
  const int g = l >> 4, c = l & 15;
  const int wr = w >> 1, wc = w & 1;
  const int sr = t >> 2, seg = t & 3;
  const float* Ap = A + (size_t)(m0 + (sr & 31)) * CD + seg * 8;
  const float* Bp = B + (size_t)(n0 + sr) * CD + seg * 8;
  f32x4 acc[2] = {};
  for (int k0 = 0; k0 < CD; k0 += 32) {
    float4 a1 = make_float4(0.f, 0.f, 0.f, 0.f), a2 = a1;
    if (t < 128) { a1 = *(const float4*)(Ap + k0); a2 = *(const float4*)(Ap + k0 + 4); }
    const float4 b1 = *(const float4*)(Bp + k0);
    const float4 b2 = *(const float4*)(Bp + k0 + 4);
    __syncthreads();
    if (t < 128) *(short8v*)&As[sr][seg * 8] = cvt8(a1, a2);
    *(short8v*)&Bs[sr][seg * 8] = cvt8(b1, b2);
    __syncthreads();
    const short8v af = *(const short8v*)&As[wr * 16 + c][g * 8];
    const short8v bf0 = *(const short8v*)&Bs[wc * 32 + c][g * 8];
    const short8v bf1 = *(const short8v*)&Bs[wc * 32 + 16 + c][g * 8];
    acc[0] = __builtin_amdgcn_mfma_f32_16x16x32_bf16(af, bf0, acc[0], 0, 0, 0);
    acc[1] = __builtin_amdgcn_mfma_f32_16x16x32_bf16(af, bf1, acc[1], 0, 0, 0);
  }
#pragma unroll
  for (int ni = 0; ni < 2; ++ni) {
    const int col = n0 + wc * 32 + ni * 16 + c;
    const float bb = bias[col];
    if (sel == 2) {
      const int mb = m0 + wr * 16 + g * 4;
      const int pidx = (mb & ~31) + ((mb >> 4) & 1) * 4 + ((mb >> 2) & 3) * 8;
      uint2 pk;
      const float v0 = acc[ni][0] + bb, v1 = acc[ni][1] + bb;
      const float v2 = acc[ni][2] + bb, v3 = acc[ni][3] + bb;
      pk.x = (unsigned)(unsigned short)bfr(v0) | ((unsigned)(unsigned short)bfr(v1) << 16);
      pk.y = (unsigned)(unsigned short)bfr(v2) | ((unsigned)(unsigned short)bfr(v3) << 16);
      *(uint2*)&VT[(size_t)col * N_TOK + pidx] = pk;
    } else {
      short* Ct = (sel == 0) ? QB : KB;
      const float qs = (sel == 0) ? QSC : 1.f;
#pragma unroll
      for (int q = 0; q < 4; ++q) {
        const int m = m0 + wr * 16 + g * 4 + q;
        Ct[(size_t)m * CD + col] = bfr((acc[ni][q] + bb) * qs);
      }
    }
  }
}

// ------------------------- Gram G = X X^T via split-bf16 (hi+lo) MFMA
__global__ __launch_bounds__(256) void gemm_syr2_k(const float* __restrict__ A,
    float* __restrict__ C) {
  __shared__ __align__(16) short AsH[64][40];
  __shared__ __align__(16) short AsL[64][40];
  __shared__ __align__(16) short BsH[64][40];
  __shared__ __align__(16) short BsL[64][40];
  int bid = blockIdx.x;
  int bi = (int)((sqrtf(8.f * (float)bid + 1.f) - 1.f) * 0.5f);
  while ((bi + 1) * (bi + 2) / 2 <= bid) ++bi;
  while (bi * (bi + 1) / 2 > bid) --bi;
  const int bj = bid - bi * (bi + 1) / 2;
  const int m0 = bi * 64, n0 = bj * 64;
  const int t = threadIdx.x;
  const int w = t >> 6, l = t & 63;
  const int g = l >> 4, c = l & 15;
  const int wr = w >> 1, wc = w & 1;
  const int sr = t >> 2, seg = t & 3;
  const float* Ap = A + (size_t)(m0 + sr) * CD + seg * 8;
  const float* Bp = A + (size_t)(n0 + sr) * CD + seg * 8;
  f32x4 acc[2][2] = {};
  for (int k0 = 0; k0 < CD; k0 += 32) {
    const float4 a1 = *(const float4*)(Ap + k0);
    const float4 a2 = *(const float4*)(Ap + k0 + 4);
    const float4 b1 = *(const float4*)(Bp + k0);
    const float4 b2 = *(const float4*)(Bp + k0 + 4);
    __syncthreads();
    short8v h8, l8;
    split8(a1, a2, h8, l8);
    *(short8v*)&AsH[sr][seg * 8] = h8;
    *(short8v*)&AsL[sr][seg * 8] = l8;
    split8(b1, b2, h8, l8);
    *(short8v*)&BsH[sr][seg * 8] = h8;
    *(short8v*)&BsL[sr][seg * 8] = l8;
    __syncthreads();
    short8v afH[2], afL[2], bfH[2], bfL[2];
#pragma unroll
    for (int mi = 0; mi < 2; ++mi) {
      afH[mi] = *(const short8v*)&AsH[wr * 32 + mi * 16 + c][g * 8];
      afL[mi] = *(const short8v*)&AsL[wr * 32 + mi * 16 + c][g * 8];
    }
#pragma unroll
    for (int ni = 0; ni < 2; ++ni) {
      bfH[ni] = *(const short8v*)&BsH[wc * 32 + ni * 16 + c][g * 8];
      bfL[ni] = *(const short8v*)&BsL[wc * 32 + ni * 16 + c][g * 8];
    }
#pragma unroll
    for (int mi = 0; mi < 2; ++mi)
#pragma unroll
      for (int ni = 0; ni < 2; ++ni) {
        acc[mi][ni] = __builtin_amdgcn_mfma_f32_16x16x32_bf16(afH[mi], bfH[ni], acc[mi][ni], 0, 0, 0);
        acc[mi][ni] = __builtin_amdgcn_mfma_f32_16x16x32_bf16(afH[mi], bfL[ni], acc[mi][ni], 0, 0, 0);
        acc[mi][ni] = __builtin_amdgcn_mfma_f32_16x16x32_bf16(afL[mi], bfH[ni], acc[mi][ni], 0, 0, 0);
      }
  }
#pragma unroll
  for (int mi = 0; mi < 2; ++mi)
#pragma unroll
    for (int ni = 0; ni < 2; ++ni) {
      const int col = n0 + wc * 32 + ni * 16 + c;
#pragma unroll
      for (int q = 0; q < 4; ++q) {
        const int m = m0 + wr * 32 + mi * 16 + g * 4 + q;
        const float v = acc[mi][ni][q];
        C[(size_t)m * N_TOK + col] = v;
        C[(size_t)col * N_TOK + m] = v;
      }
    }
}

// ------------------------------------------------------------ conv2 (8ch)
__global__ __launch_bounds__(256) void conv2_k(const float* __restrict__ t1,
    const float* __restrict__ w, const float* __restrict__ b,
    float* __restrict__ gp) {
  __shared__ float ws3[9 * 8 * 132];
  const int t = threadIdx.x;
  for (int e = t; e < 9216; e += 256) {
    int r = e >> 10;
    int rem = e & 1023;
    int co = rem >> 7;
    int ci = rem & 127;
    ws3[(r * 8 + co) * 132 + ci] = w[((size_t)co * 128 + ci) * 9 + r];
  }
  __syncthreads();
  const int pix = blockIdx.x * 32 + (t >> 3);
  const int co = t & 7;
  const int y = pix / 56, x = pix - y * 56;
  float acc = b[co];
  for (int ky = 0; ky < 3; ++ky) {
    int yy = y + ky - 1;
    if (yy < 0 || yy >= 56) continue;
    for (int kx = 0; kx < 3; ++kx) {
      int xx = x + kx - 1;
      if (xx < 0 || xx >= 56) continue;
      const float4* tp = (const float4*)&t1[(size_t)(yy * 56 + xx) * 128];
      const float* wp = &ws3[((ky * 3 + kx) * 8 + co) * 132];
#pragma unroll
      for (int c4 = 0; c4 < 32; ++c4) {
        const float4 tv = tp[c4];
        const float4 wv = *(const float4*)&wp[c4 * 4];
        acc += tv.x * wv.x + tv.y * wv.y + tv.z * wv.z + tv.w * wv.w;
      }
    }
  }
  gp[pix * 8 + co] = 1.f / (1.f + expf(-acc));
}

// ------------------------------------------------------------- row ||x||^2
__global__ __launch_bounds__(64) void rowsq_k(const float* __restrict__ x,
                                              float* __restrict__ sq) {
  const int i = blockIdx.x, lane = threadIdx.x;
  const float4 v = ((const float4*)&x[(size_t)i * CD])[lane];
  float s = v.x * v.x + v.y * v.y + v.z * v.z + v.w * v.w;
#pragma unroll
  for (int m = 1; m < 64; m <<= 1) s += __shfl_xor(s, m, 64);
  if (lane == 0) sq[i] = s;
}

// -------------------------------------------------- top-16 NN + in-degree
__global__ __launch_bounds__(256) void topk_k(const float* __restrict__ G,
    const float* __restrict__ sq, int* __restrict__ near) {
  __shared__ unsigned long long wmin[4];
  const int i = blockIdx.x;
  const int t = threadIdx.x;
  const float sqi = sq[i];
  unsigned long long key[13];
#pragma unroll
  for (int e = 0; e < 13; ++e) {
    int j = t + (e << 8);
    float d2 = INFINITY;
    if (j < N_TOK) d2 = (sqi - 2.f * G[(size_t)i * N_TOK + j]) + sq[j];
    key[e] = ((unsigned long long)f2mono(d2) << 32) | (unsigned)j;
  }
  unsigned long long last = 0ull;
#pragma unroll 1
  for (int r = 0; r < 16; ++r) {
    unsigned long long best = ~0ull;
#pragma unroll
    for (int e = 0; e < 13; ++e) {
      bool ok = (key[e] > last) && (key[e] < best);
      best = ok ? key[e] : best;
    }
#pragma unroll
    for (int m = 1; m < 64; m <<= 1) {
      unsigned long long o = sx64(best, m);
      best = (o < best) ? o : best;
    }
    __syncthreads();
    if ((t & 63) == 0) wmin[t >> 6] = best;
    __syncthreads();
    unsigned long long b0 = wmin[0] < wmin[1] ? wmin[0] : wmin[1];
    unsigned long long b1 = wmin[2] < wmin[3] ? wmin[2] : wmin[3];
    best = b0 < b1 ? b0 : b1;
    if (t == 0) atomicAdd(&near[(unsigned)(best & 0xffffffffu)], 1);
    last = best;
  }
}

// ------------------------------------------------------------- max(near)
__global__ __launch_bounds__(256) void nearmax_k(const int* __restrict__ near,
                                                 int* __restrict__ nmax) {
  __shared__ int sm[4];
  const int t = threadIdx.x;
  int m = 0;
  for (int j = t; j < N_TOK; j += 256) m = max(m, near[j]);
#pragma unroll
  for (int s = 1; s < 64; s <<= 1) m = max(m, __shfl_xor(m, s, 64));
  if ((t & 63) == 0) sm[t >> 6] = m;
  __syncthreads();
  if (t == 0) nmax[0] = max(max(sm[0], sm[1]), max(sm[2], sm[3]));
}

// ------------------------------------------------ qk_in = x + emb[ni(near)]
__global__ __launch_bounds__(256) void qkin_k(const float* __restrict__ x,
    const int* __restrict__ near, const int* __restrict__ nmax,
    const float* __restrict__ emb, float* __restrict__ qkin) {
  const int i = blockIdx.x, t = threadIdx.x;
  const float nf = (float)near[i], mf = (float)nmax[0];
  const int ni = (int)(nf / mf * 9.0f);
  qkin[(size_t)i * CD + t] = x[(size_t)i * CD + t] + emb[ni * CD + t];
}

// ---------------------------------- gp [tok][8] -> gpT [8][tok], * log2e
__global__ __launch_bounds__(256) void gpt_k(const float* __restrict__ gp,
                                             float* __restrict__ gpT) {
  const int e = blockIdx.x * 256 + threadIdx.x;
  const int i = e >> 3, h = e & 7;
  gpT[h * N_TOK + i] = gp[e] * LOG2E;
}

// ---- flash attention v5: 32 queries/block shared by 4 j-quarter waves
// grid (98, 8). Each wave: 2 query groups (16 cols each), slot-aligned PV,
// defer-max, K prefetch. In-block LDS combine writes normalized O directly.
__global__ __launch_bounds__(256) void attn_v5_k(const short* __restrict__ Qb,
    const short* __restrict__ Kb, const short* __restrict__ Vt,
    const float* __restrict__ gpT, float* __restrict__ O1) {
  __shared__ float o_l[4][32][36];
  __shared__ float ml_l[4][32][2];
  const int h = blockIdx.y;
  const int qb = blockIdx.x * 32;
  const int t = threadIdx.x;
  const int w = t >> 6, l = t & 63;
  const int g = l >> 4, c = l & 15;
  const size_t hoff = (size_t)h * DH;
  short8v qf[2];
  float gpi[2];
#pragma unroll
  for (int gr = 0; gr < 2; ++gr) {
    qf[gr] = *(const short8v*)&Qb[(size_t)(qb + gr * 16 + c) * CD + hoff + g * 8];
    gpi[gr] = gpT[h * N_TOK + qb + gr * 16 + c];
  }
  const int jt0 = w ? (13 + 12 * (w - 1)) : 0;
  const int jt1 = jt0 + (w ? 12 : 13);
  float mr[2] = {-INFINITY, -INFINITY};
  float lp[2] = {0.f, 0.f};
  f32x4 oa[2][2] = {};
  const f32x4 zz = {0.f, 0.f, 0.f, 0.f};

  short8v kf[4];
#pragma unroll
  for (int sub = 0; sub < 4; ++sub)
    kf[sub] = *(const short8v*)&Kb[(size_t)(jt0 * 64 + sub * 16 + c) * CD + hoff + g * 8];

  for (int jt = jt0; jt < jt1; ++jt) {
    const int j0 = jt * 64;
    // QK^T both groups: s[gr][sub][q] = S[slot sub*16+g*4+q][query gr*16+c]
    f32x4 s[2][4];
#pragma unroll
    for (int sub = 0; sub < 4; ++sub) {
      s[0][sub] = __builtin_amdgcn_mfma_f32_16x16x32_bf16(kf[sub], qf[0], zz, 0, 0, 0);
      s[1][sub] = __builtin_amdgcn_mfma_f32_16x16x32_bf16(kf[sub], qf[1], zz, 0, 0, 0);
    }
    // V fragments (shared by both groups), issued before softmax
    short8v vf[4];
#pragma unroll
    for (int ch = 0; ch < 2; ++ch)
#pragma unroll
      for (int ds = 0; ds < 2; ++ds)
        vf[ch * 2 + ds] = *(const short8v*)&Vt[(hoff + ds * 16 + c) * (size_t)N_TOK + j0 + ch * 32 + g * 8];
    // prefetch next K tile (kf dead after the QK above)
    if (jt + 1 < jt1) {
#pragma unroll
      for (int sub = 0; sub < 4; ++sub)
        kf[sub] = *(const short8v*)&Kb[(size_t)(j0 + 64 + sub * 16 + c) * CD + hoff + g * 8];
    }
    float4 gj[4];
#pragma unroll
    for (int sub = 0; sub < 4; ++sub)
      gj[sub] = *(const float4*)&gpT[h * N_TOK + j0 + sub * 16 + g * 4];
#pragma unroll
    for (int gr = 0; gr < 2; ++gr) {
      // bias (log2 domain)
      float sv[16];
#pragma unroll
      for (int sub = 0; sub < 4; ++sub) {
        sv[sub * 4 + 0] = s[gr][sub][0] + fabsf(gpi[gr] - gj[sub].x);
        sv[sub * 4 + 1] = s[gr][sub][1] + fabsf(gpi[gr] - gj[sub].y);
        sv[sub * 4 + 2] = s[gr][sub][2] + fabsf(gpi[gr] - gj[sub].z);
        sv[sub * 4 + 3] = s[gr][sub][3] + fabsf(gpi[gr] - gj[sub].w);
      }
      // lane-local tree max
      float a0 = fmaxf(sv[0], sv[1]),  a1 = fmaxf(sv[2], sv[3]);
      float a2 = fmaxf(sv[4], sv[5]),  a3 = fmaxf(sv[6], sv[7]);
      float a4 = fmaxf(sv[8], sv[9]),  a5 = fmaxf(sv[10], sv[11]);
      float a6 = fmaxf(sv[12], sv[13]), a7 = fmaxf(sv[14], sv[15]);
      const float mx = fmaxf(fmaxf(fmaxf(a0, a1), fmaxf(a2, a3)),
                             fmaxf(fmaxf(a4, a5), fmaxf(a6, a7)));
      // defer-max rebase (rare)
      if (!__all(mx - mr[gr] <= 11.f)) {
        float mn = mx;
        mn = fmaxf(mn, __shfl_xor(mn, 16, 64));
        mn = fmaxf(mn, __shfl_xor(mn, 32, 64));
        mn = fmaxf(mn, mr[gr]);
        const float sc = __builtin_amdgcn_exp2f(mr[gr] - mn);
        oa[gr][0][0] *= sc; oa[gr][0][1] *= sc; oa[gr][0][2] *= sc; oa[gr][0][3] *= sc;
        oa[gr][1][0] *= sc; oa[gr][1][1] *= sc; oa[gr][1][2] *= sc; oa[gr][1][3] *= sc;
        lp[gr] *= sc;
        mr[gr] = mn;
      }
      // exp2 + truncate to bf16 (consistent for l-sum and PV)
      unsigned pu[16];
      float pvt[16];
#pragma unroll
      for (int e = 0; e < 16; ++e) {
        const float p = __builtin_amdgcn_exp2f(sv[e] - mr[gr]);
        pu[e] = __float_as_uint(p) & 0xffff0000u;
        pvt[e] = __uint_as_float(pu[e]);
      }
      const float s0 = (pvt[0] + pvt[1]) + (pvt[2] + pvt[3]);
      const float s1 = (pvt[4] + pvt[5]) + (pvt[6] + pvt[7]);
      const float s2 = (pvt[8] + pvt[9]) + (pvt[10] + pvt[11]);
      const float s3 = (pvt[12] + pvt[13]) + (pvt[14] + pvt[15]);
      lp[gr] += (s0 + s1) + (s2 + s3);
      // pack P pairs
      unsigned pk8[8];
#pragma unroll
      for (int sub = 0; sub < 4; ++sub) {
        pk8[2 * sub + 0] = __builtin_amdgcn_perm(pu[4 * sub + 1], pu[4 * sub + 0], 0x07060302u);
        pk8[2 * sub + 1] = __builtin_amdgcn_perm(pu[4 * sub + 3], pu[4 * sub + 2], 0x07060302u);
      }
      union { unsigned u[4]; short8v s; } pf0, pf1;
      pf0.u[0] = pk8[0]; pf0.u[1] = pk8[1]; pf0.u[2] = pk8[2]; pf0.u[3] = pk8[3];
      pf1.u[0] = pk8[4]; pf1.u[1] = pk8[5]; pf1.u[2] = pk8[6]; pf1.u[3] = pk8[7];
      // PV: O^T[d][query]; k-enum = slot order, P frag = own registers
      oa[gr][0] = __builtin_amdgcn_mfma_f32_16x16x32_bf16(vf[0], pf0.s, oa[gr][0], 0, 0, 0);
      oa[gr][1] = __builtin_amdgcn_mfma_f32_16x16x32_bf16(vf[1], pf0.s, oa[gr][1], 0, 0, 0);
      oa[gr][0] = __builtin_amdgcn_mfma_f32_16x16x32_bf16(vf[2], pf1.s, oa[gr][0], 0, 0, 0);
      oa[gr][1] = __builtin_amdgcn_mfma_f32_16x16x32_bf16(vf[3], pf1.s, oa[gr][1], 0, 0, 0);
    }
  }
  // ---- per-wave partials to LDS
#pragma unroll
  for (int gr = 0; gr < 2; ++gr) {
    lp[gr] += __shfl_xor(lp[gr], 16, 64);
    lp[gr] += __shfl_xor(lp[gr], 32, 64);
#pragma unroll
    for (int ds = 0; ds < 2; ++ds)
      *(f32x4*)&o_l[w][gr * 16 + c][ds * 16 + g * 4] = oa[gr][ds];
    if (g == 0) {
      ml_l[w][gr * 16 + c][0] = mr[gr];
      ml_l[w][gr * 16 + c][1] = lp[gr];
    }
  }
  __syncthreads();
  // ---- combine 4 quarters: thread -> (q = t>>3, d0 = (t&7)*4)
  const int q = t >> 3, d0 = (t & 7) * 4;
  const float M = fmaxf(fmaxf(ml_l[0][q][0], ml_l[1][q][0]),
                        fmaxf(ml_l[2][q][0], ml_l[3][q][0]));
  float den = 0.f;
  f32x4 num = {0.f, 0.f, 0.f, 0.f};
#pragma unroll
  for (int sp = 0; sp < 4; ++sp) {
    const float wg = __builtin_amdgcn_exp2f(ml_l[sp][q][0] - M);
    den += wg * ml_l[sp][q][1];
    const f32x4 ov = *(const f32x4*)&o_l[sp][q][d0];
    num[0] += wg * ov[0]; num[1] += wg * ov[1];
    num[2] += wg * ov[2]; num[3] += wg * ov[3];
  }
  const float inv = 1.f / den;
  f32x4 r = {num[0] * inv, num[1] * inv, num[2] * inv, num[3] * inv};
  *(f32x4*)&O1[(size_t)(qb + q) * CD + hoff + d0] = r;
}

// ---------------------- LayerNorm (+residual) (+optional row-sq output)
__global__ __launch_bounds__(256) void ln_k(const float* __restrict__ xin,
    const float* __restrict__ add, const float* __restrict__ g,
    const float* __restrict__ b, float* __restrict__ xout,
    float* __restrict__ sqout) {
  __shared__ float red1[4];
  __shared__ float red2[4];
  const int i = blockIdx.x, t = threadIdx.x;
  float v = xin[(size_t)i * CD + t];
  if (add) v += add[(size_t)i * CD + t];
  float s = v;
#pragma unroll
  for (int m = 1; m < 64; m <<= 1) s += __shfl_xor(s, m, 64);
  if ((t & 63) == 0) red1[t >> 6] = s;
  __syncthreads();
  const float mean = (red1[0] + red1[1] + red1[2] + red1[3]) * (1.f / 256.f);
  const float d = v - mean;
  float s2 = d * d;
#pragma unroll
  for (int m = 1; m < 64; m <<= 1) s2 += __shfl_xor(s2, m, 64);
  if ((t & 63) == 0) red2[t >> 6] = s2;
  __syncthreads();
  const float var = (red2[0] + red2[1] + red2[2] + red2[3]) * (1.f / 256.f);
  const float xo = d * rsqrtf(var + 1e-5f) * g[t] + b[t];
  xout[(size_t)i * CD + t] = xo;
  if (sqout) {
    float s3 = xo * xo;
#pragma unroll
    for (int m = 1; m < 64; m <<= 1) s3 += __shfl_xor(s3, m, 64);
    __syncthreads();
    if ((t & 63) == 0) red1[t >> 6] = s3;
    __syncthreads();
    if (t == 0) sqout[i] = red1[0] + red1[1] + red1[2] + red1[3];
  }
}

// ---------------------------------------------------------------- launch
extern "C" void kernel_launch(void* const* d_in, const int* in_sizes, int n_in,
                              void* d_out, int out_size, void* d_ws, size_t ws_size,
                              hipStream_t stream) {
  const float* src  = (const float*)d_in[0];
  const float* c1w  = (const float*)d_in[1];
  const float* c1b  = (const float*)d_in[2];
  const float* c2w  = (const float*)d_in[3];
  const float* c2b  = (const float*)d_in[4];
  const float* nemb = (const float*)d_in[5];
  const float* Wq   = (const float*)d_in[6];
  const float* bq   = (const float*)d_in[7];
  const float* Wk   = (const float*)d_in[8];
  const float* bk   = (const float*)d_in[9];
  const float* Wv   = (const float*)d_in[10];
  const float* bv   = (const float*)d_in[11];
  const float* Wo   = (const float*)d_in[12];
  const float* bo   = (const float*)d_in[13];
  const float* W1   = (const float*)d_in[14];
  const float* b1   = (const float*)d_in[15];
  const float* W2   = (const float*)d_in[16];
  const float* b2   = (const float*)d_in[17];
  const float* ln1g = (const float*)d_in[18];
  const float* ln1b = (const float*)d_in[19];
  const float* ln2g = (const float*)d_in[20];
  const float* ln2b = (const float*)d_in[21];
  const float* ng   = (const float*)d_in[22];
  const float* nb   = (const float*)d_in[23];

  float* ws = (float*)d_ws;
  const size_t NC = (size_t)N_TOK * CD;          // 802816
  float* X    = ws;
  float* QKIN = X + NC;
  float* O1   = QKIN + NC;
  float* TMP  = O1 + NC;
  float* FF1  = TMP + NC;                        // 3136*1024
  float* G    = FF1 + (size_t)N_TOK * DFFD;      // 3136*3136 (also conv1 partials)
  float* T1   = G + (size_t)N_TOK * N_TOK;       // 3136*128
  float* GP   = T1 + (size_t)N_TOK * 128;        // 3136*8
  float* GPT  = GP + (size_t)N_TOK * NHD;        // 3136*8
  float* SQF  = GPT + (size_t)N_TOK * NHD;       // 3136
  short* QB16 = (short*)(SQF + N_TOK);
  short* KB16 = QB16 + NC;
  short* VT16 = KB16 + NC;
  float* WTC  = (float*)(VT16 + NC);             // 9*128*256 = 294912
  int*   NEAR = (int*)(WTC + 294912);
  int*   NMAX = NEAR + N_TOK;

  // tokens + conv positional encoder (direct conv, no im2col)
  transpose_k<<<dim3(98, 8), 256, 0, stream>>>(src, X, 256, N_TOK);
  wtr_k<<<1152, 256, 0, stream>>>(c1w, WTC);
  conv1_k<<<dim3(2, 98, 3), 256, 0, stream>>>(X, WTC, G);
  convred_k<<<1568, 256, 0, stream>>>(G, c1b, T1);
  conv2_k<<<98, 256, 0, stream>>>(T1, c2w, c2b, GP);
  gpt_k<<<98, 256, 0, stream>>>(GP, GPT);
  rowsq_k<<<N_TOK, 64, 0, stream>>>(X, SQF);

  for (int l = 0; l < 4; ++l) {
    // ---- kNN graph -> near counts (split-bf16 MFMA Gram)
    gemm_syr2_k<<<1225, 256, 0, stream>>>(X, G);
    (void)hipMemsetAsync(NEAR, 0, N_TOK * sizeof(int), stream);
    topk_k<<<N_TOK, 256, 0, stream>>>(G, SQF, NEAR);
    nearmax_k<<<1, 256, 0, stream>>>(NEAR, NMAX);
    qkin_k<<<N_TOK, 256, 0, stream>>>(X, NEAR, NMAX, nemb, QKIN);
    // ---- fused Q/K/V projections (32-row tiles)
    proj32_k<<<dim3(4, 98, 3), 256, 0, stream>>>(QKIN, X,
        Wq + (size_t)l * 65536, Wk + (size_t)l * 65536, Wv + (size_t)l * 65536,
        bq + l * 256, bk + l * 256, bv + l * 256, QB16, KB16, VT16);
    // ---- attention (shared K/V across 4 j-quarter waves, in-block combine)
    attn_v5_k<<<dim3(98, 8), 256, 0, stream>>>(QB16, KB16, VT16, GPT, O1);
    gemm32_k<0><<<dim3(4, 98), 256, 0, stream>>>(O1, Wo + (size_t)l * 65536, bo + l * 256, TMP, 256, 256);
    ln_k<<<N_TOK, 256, 0, stream>>>(X, TMP, ln1g + l * 256, ln1b + l * 256, X, nullptr);
    // ---- FFN
    gemm32_k<1><<<dim3(16, 98), 256, 0, stream>>>(X, W1 + (size_t)l * 262144, b1 + l * 1024, FF1, 1024, 256);
    gemm32_k<0><<<dim3(4, 98), 256, 0, stream>>>(FF1, W2 + (size_t)l * 262144, b2 + l * 256, TMP, 256, 1024);
    ln_k<<<N_TOK, 256, 0, stream>>>(X, TMP, ln2g + l * 256, ln2b + l * 256, X, SQF);
  }
  // final LN + transpose to [1,C,H,W]
  ln_k<<<N_TOK, 256, 0, stream>>>(X, nullptr, ng, nb, TMP, nullptr);
  transpose_k<<<dim3(8, 98), 256, 0, stream>>>(TMP, (float*)d_out, N_TOK, 256);
}